// Round 3
// baseline (3526.392 us; speedup 1.0000x reference)
//
#include <hip/hip_runtime.h>
#include <hip/hip_bf16.h>

// STMA block, MI355X. Round 3: f32 inputs/outputs (reference dtypes are all
// jnp.float32). f32 accumulation; motion_feat stored bf16 (67 MB scratch).

typedef __hip_bfloat16 bf16;

__device__ __forceinline__ float b2f(bf16 v){ return __bfloat162float(v); }
__device__ __forceinline__ bf16 f2b(float v){ return __float2bfloat16(v); }
__device__ __forceinline__ float geluf(float x){ return 0.5f*x*(1.0f+erff(x*0.7071067811865475f)); }
__device__ __forceinline__ float siluf(float x){ return x/(1.0f+expf(-x)); }

__device__ __forceinline__ float wsum(float v){
#pragma unroll
  for (int o=32;o>0;o>>=1) v += __shfl_xor(v,o,64);
  return v;
}
__device__ __forceinline__ float wmax(float v){
#pragma unroll
  for (int o=32;o>0;o>>=1) v = fmaxf(v, __shfl_xor(v,o,64));
  return v;
}

// top-2-of-8 softmax gate weights (deterministic, per-thread redundant)
__device__ __forceinline__ void top2gate(const float* lg, float* g){
  int i1 = 0; float v1 = lg[0];
#pragma unroll
  for (int e=1;e<8;e++) if (lg[e] > v1){ v1 = lg[e]; i1 = e; }
  int i2 = 0; float v2 = -1e30f;
#pragma unroll
  for (int e=0;e<8;e++) if (e != i1 && lg[e] > v2){ v2 = lg[e]; i2 = e; }
  float wA = 1.f/(1.f + expf(v2 - v1));
#pragma unroll
  for (int e=0;e<8;e++) g[e] = 0.f;
  g[i1] = wA; g[i2] = 1.f - wA;
}

// softmax rows of body_w (8x8)
__global__ __launch_bounds__(64) void k_bw(const float* __restrict__ body_w, float* __restrict__ bwv){
  int t = threadIdx.x;
  if (t < 8){
    float v[8]; float mx = -1e30f;
#pragma unroll
    for (int j=0;j<8;j++){ v[j] = body_w[t*8+j]; mx = fmaxf(mx, v[j]); }
    float s = 0.f;
#pragma unroll
    for (int j=0;j<8;j++){ v[j] = expf(v[j]-mx); s += v[j]; }
#pragma unroll
    for (int j=0;j<8;j++) bwv[t*8+j] = v[j]/s;
  }
}

// ---------- fused text pipeline: LN(256)+pos -> gate -> MoE(256->1024->256) -> gelu -> proj(256->128)
// one block (256 threads) per text token (4928)
__global__ __launch_bounds__(256) void k_text(
    const float* __restrict__ xf, const float* __restrict__ tg, const float* __restrict__ tb,
    const float* __restrict__ tpos, const float* __restrict__ gw,
    const float* __restrict__ fc1w, const float* __restrict__ fc1b,
    const float* __restrict__ fc2w, const float* __restrict__ fc2b,
    const float* __restrict__ pw, const float* __restrict__ pb,
    float* __restrict__ tfeat){
  int tok = blockIdx.x; int tid = threadIdx.x;
  int n = tok % 77;
  __shared__ float xs[256], hs[1024], redw[32], lgs[8];
  int w = tid >> 6, ln = tid & 63;

  float xv = xf[tok*256 + tid];
  float s1 = wsum(xv);
  if (ln == 0) redw[w] = s1;
  __syncthreads();
  float mean = (redw[0]+redw[1]+redw[2]+redw[3]) * (1.f/256.f);
  __syncthreads();
  float c = xv - mean;
  float s2 = wsum(c*c);
  if (ln == 0) redw[w] = s2;
  __syncthreads();
  float var = (redw[0]+redw[1]+redw[2]+redw[3]) * (1.f/256.f);
  float r = rsqrtf(var + 1e-5f);
  float xn = c*r*tg[tid] + tb[tid] + tpos[n*256 + tid];
  xs[tid] = xn;
  __syncthreads();   // also fences redw before gate reuse

  // gate logits: lg[e] = sum_c xs[c]*gw[c*8+e]
  float lp[8];
#pragma unroll
  for (int e=0;e<8;e++) lp[e] = xn * gw[tid*8 + e];
#pragma unroll
  for (int e=0;e<8;e++) lp[e] = wsum(lp[e]);
  if (ln == 0){
#pragma unroll
    for (int e=0;e<8;e++) redw[w*8+e] = lp[e];
  }
  __syncthreads();
  if (tid < 8) lgs[tid] = redw[tid] + redw[8+tid] + redw[16+tid] + redw[24+tid];
  __syncthreads();
  float lg[8];
#pragma unroll
  for (int e=0;e<8;e++) lg[e] = lgs[e];
  float g[8]; top2gate(lg, g);   // identical across all threads -> uniform branches

  float acc = 0.f;
  for (int e=0;e<8;e++){
    float ge = g[e];
    if (ge != 0.f){
      float hh[4];
#pragma unroll
      for (int i=0;i<4;i++) hh[i] = fc1b[e*1024 + tid + 256*i];
      const float* w1 = fc1w + (size_t)e*256*1024;
      for (int k=0;k<256;k++){
        float xk = xs[k];
#pragma unroll
        for (int i=0;i<4;i++) hh[i] += xk * w1[k*1024 + tid + 256*i];
      }
#pragma unroll
      for (int i=0;i<4;i++) hs[tid + 256*i] = geluf(hh[i]);
    }
    __syncthreads();
    if (ge != 0.f){
      const float* w2 = fc2w + (size_t)e*1024*256;
      float a2 = 0.f;
      for (int k=0;k<1024;k++) a2 += hs[k] * w2[k*256 + tid];
      acc += ge*(a2 + fc2b[e*256 + tid]);
    }
    __syncthreads();
  }
  // proj: gelu(acc) @ (256x128) + b
  hs[tid] = geluf(acc);
  __syncthreads();
  if (tid < 128){
    float a = pb[tid];
    for (int k=0;k<256;k++) a += hs[k] * pw[k*128 + tid];
    tfeat[tok*128 + tid] = a;
  }
}

// ---------- fused motion pipeline: LN(64)+pos -> gate -> MoE(64->256->64) -> gelu -> proj(64->256)
// one block (64 threads = 1 wave) per (b,t,h) token (131072)
__global__ __launch_bounds__(64) void k_motion(
    const float* __restrict__ x, const float* __restrict__ ng, const float* __restrict__ nb,
    const float* __restrict__ mpos, const float* __restrict__ gw,
    const float* __restrict__ fc1w, const float* __restrict__ fc1b,
    const float* __restrict__ fc2w, const float* __restrict__ fc2b,
    const float* __restrict__ pw, const float* __restrict__ pb,
    bf16* __restrict__ mf){
  int tok = blockIdx.x; int d = threadIdx.x;
  __shared__ float xs[64], hs[256], gy[64];
  float xv = x[tok*64 + d];
  float m = wsum(xv) * (1.f/64.f);
  float c = xv - m;
  float var = wsum(c*c) * (1.f/64.f);
  float r = rsqrtf(var + 1e-5f);
  int h = tok & 7; int t = (tok >> 3) & 255;
  float xn = c*r*ng[d] + nb[d] + mpos[(t*8+h)*64 + d];
  xs[d] = xn;
  __syncthreads();

  float lg[8];
#pragma unroll
  for (int e=0;e<8;e++) lg[e] = wsum(xn * gw[d*8 + e]);
  float g[8]; top2gate(lg, g);   // wave-uniform

  float acc = 0.f;
  for (int e=0;e<8;e++){
    float ge = g[e];
    if (ge != 0.f){
      float hh[4];
#pragma unroll
      for (int i=0;i<4;i++) hh[i] = fc1b[e*256 + d + 64*i];
      const float* w1 = fc1w + (size_t)e*64*256;
      for (int k=0;k<64;k++){
        float xk = xs[k];
#pragma unroll
        for (int i=0;i<4;i++) hh[i] += xk * w1[k*256 + d + 64*i];
      }
#pragma unroll
      for (int i=0;i<4;i++) hs[d + 64*i] = geluf(hh[i]);
    }
    __syncthreads();
    if (ge != 0.f){
      const float* w2 = fc2w + (size_t)e*256*64;
      float a2 = 0.f;
      for (int k=0;k<256;k++) a2 += hs[k] * w2[k*64 + d];
      acc += ge*(a2 + fc2b[e*64 + d]);
    }
    __syncthreads();
  }
  gy[d] = geluf(acc);
  __syncthreads();
  float a[4];
#pragma unroll
  for (int i=0;i<4;i++) a[i] = pb[d + 64*i];
  for (int k=0;k<64;k++){
    float gk = gy[k];
#pragma unroll
    for (int i=0;i<4;i++) a[i] += gk * pw[k*256 + d + 64*i];
  }
#pragma unroll
  for (int i=0;i<4;i++) mf[(size_t)tok*256 + d + 64*i] = f2b(a[i]);
}

// eo = silu(emb) @ (2048x1024) + b
__global__ __launch_bounds__(256) void k_eo(const float* __restrict__ emb, const float* __restrict__ ew,
                     const float* __restrict__ ebias, float* __restrict__ eo){
  int b = blockIdx.x >> 2; int q = blockIdx.x & 3; int tid = threadIdx.x;
  __shared__ float se[2048];
#pragma unroll
  for (int i=0;i<8;i++){ int k = tid + 256*i; se[k] = siluf(emb[b*2048 + k]); }
  __syncthreads();
  int c = q*256 + tid;
  float a = ebias[c];
  for (int k=0;k<2048;k++) a += se[k] * ew[k*1024 + c];
  eo[b*1024 + c] = a;
}

// key = softmax over N=333 (per b,h,d); attn[b,h,d,l] = sum_n key*value. one block per (b,h)
__global__ __launch_bounds__(256) void k_attn(const float* __restrict__ tfeat, const bf16* __restrict__ mf,
                       const float* __restrict__ src_mask, const int* __restrict__ cond,
                       float* __restrict__ attnw){
  int b = blockIdx.x >> 3; int h = blockIdx.x & 7;
  int tid = threadIdx.x; int d = tid & 63; int part = tid >> 6;
  __shared__ float colmax[64], colsum[64], red[256];
  __shared__ float kch[4096], vch[4096];
  float tc = ((cond[b] % 10) > 0) ? 1.f : 0.f;
  float negt = (1.f - tc) * (-1e6f);

  float mx = -1e30f;
  for (int n = part; n < 333; n += 4){
    float kv;
    if (n < 77){ kv = tfeat[(b*77+n)*128 + d] + negt; }
    else { int t = n - 77; float smv = src_mask[b*256 + t];
           kv = b2f(mf[((size_t)(b*256+t)*8+h)*256 + 64 + d]) + (1.f - smv)*(-1e6f); }
    mx = fmaxf(mx, kv);
  }
  red[tid] = mx; __syncthreads();
  if (part == 0) colmax[d] = fmaxf(fmaxf(red[d],red[d+64]), fmaxf(red[d+128],red[d+192]));
  __syncthreads();
  float cm = colmax[d];
  float sacc = 0.f;
  for (int n = part; n < 333; n += 4){
    float kv;
    if (n < 77){ kv = tfeat[(b*77+n)*128 + d] + negt; }
    else { int t = n - 77; float smv = src_mask[b*256 + t];
           kv = b2f(mf[((size_t)(b*256+t)*8+h)*256 + 64 + d]) + (1.f - smv)*(-1e6f); }
    sacc += expf(kv - cm);
  }
  red[tid] = sacc; __syncthreads();
  if (part == 0) colsum[d] = red[d]+red[d+64]+red[d+128]+red[d+192];
  __syncthreads();
  float acc[16];
#pragma unroll
  for (int j=0;j<16;j++) acc[j] = 0.f;
  int l0 = part*16;
  for (int nc = 0; nc < 333; nc += 64){
    int nn = (333 - nc < 64) ? (333 - nc) : 64;
    for (int idx = tid; idx < nn*64; idx += 256){
      int rr = idx >> 6; int cc = idx & 63; int n = nc + rr;
      float kv, vv;
      if (n < 77){
        const float* trow = tfeat + (b*77+n)*128;
        kv = trow[cc] + negt;
        vv = trow[64 + cc] * tc;
      } else {
        int t = n - 77; float smv = src_mask[b*256 + t];
        const bf16* mrow = mf + ((size_t)(b*256+t)*8+h)*256;
        kv = b2f(mrow[64 + cc]) + (1.f - smv)*(-1e6f);
        vv = b2f(mrow[128 + cc]) * smv;
      }
      kch[idx] = expf(kv - colmax[cc]);
      vch[idx] = vv;
    }
    __syncthreads();
    for (int rr=0; rr<nn; rr++){
      float e = kch[rr*64 + d];
      const float* vrow = vch + rr*64 + l0;
#pragma unroll
      for (int j=0;j<16;j++) acc[j] += e * vrow[j];
    }
    __syncthreads();
  }
  float inv = 1.f / colsum[d];
  float* outp = attnw + ((size_t)(b*8+h)*64 + d)*64 + l0;
#pragma unroll
  for (int j=0;j<16;j++) outp[j] = acc[j] * inv;
}

// per (b,t): query softmax, y_t = q@attn, body mix, LN(512), modulate, silu -> sbuf (f32, in d_out)
__global__ __launch_bounds__(256) void k_j1(const bf16* __restrict__ mf, const float* __restrict__ attnw,
                     const float* __restrict__ bwv, const float* __restrict__ eo,
                     const float* __restrict__ sb_ng, const float* __restrict__ sb_nb,
                     float* __restrict__ sbuf){
  int blk = blockIdx.x; int b = blk >> 8; int t = blk & 255;
  int tid = threadIdx.x;
  __shared__ float q[512], mfl[512], red[4];
#pragma unroll
  for (int ii=0; ii<2; ii++){
    int idx = tid + ii*256; int h = idx >> 6; int dd = idx & 63;
    const bf16* mrow = mf + ((size_t)(b*256+t)*8+h)*256;
    q[idx]   = b2f(mrow[192 + dd]);
    mfl[idx] = b2f(mrow[dd]);
  }
  __syncthreads();
  int w = tid >> 6, ln = tid & 63;
  for (int h = w; h < 8; h += 4){
    float v = q[h*64 + ln];
    float mx = wmax(v);
    float e = expf(v - mx);
    float s = wsum(e);
    q[h*64 + ln] = e/s;
  }
  __syncthreads();
  float out[2];
#pragma unroll
  for (int ii=0; ii<2; ii++){
    int idx = tid + ii*256; int h = idx >> 6; int l = idx & 63;
    float a = 0.f;
    const float* ap = attnw + (size_t)(b*8+h)*4096 + l;
    for (int dd=0; dd<64; dd++) a += q[h*64 + dd] * ap[dd*64];
    float bs = 0.f;
#pragma unroll
    for (int lh=0; lh<8; lh++) bs += bwv[h*8 + lh] * mfl[lh*64 + l];
    out[ii] = a + bs;
  }
  float psum = wsum(out[0] + out[1]);
  if (ln == 0) red[w] = psum;
  __syncthreads();
  float mean = (red[0]+red[1]+red[2]+red[3]) * (1.f/512.f);
  __syncthreads();
  float c0 = out[0]-mean, c1 = out[1]-mean;
  float pv = wsum(c0*c0 + c1*c1);
  if (ln == 0) red[w] = pv;
  __syncthreads();
  float var = (red[0]+red[1]+red[2]+red[3]) * (1.f/512.f);
  float r = rsqrtf(var + 1e-5f);
#pragma unroll
  for (int ii=0; ii<2; ii++){
    int c = tid + ii*256;
    float hn = (out[ii]-mean)*r*sb_ng[c] + sb_nb[c];
    float e1 = eo[b*1024 + c], e2 = eo[b*1024 + 512 + c];
    float hm = hn*(1.f + e1) + e2;
    sbuf[(size_t)blk*512 + c] = siluf(hm);
  }
}

// out = x + sbuf @ (512x512) + b. 4 rows per block; sbuf lives in d_out (in-place safe per block)
__global__ __launch_bounds__(256) void k_out(const float* __restrict__ W,
                      const float* __restrict__ bias, const float* __restrict__ x,
                      float* __restrict__ out){
  int r0 = blockIdx.x * 4; int tid = threadIdx.x;
  __shared__ float sr[4*512];
#pragma unroll
  for (int i=0;i<8;i++){ int idx = tid + 256*i; sr[idx] = out[(size_t)r0*512 + idx]; }
  __syncthreads();
  float acc[4][2];
#pragma unroll
  for (int r=0;r<4;r++){ acc[r][0]=0.f; acc[r][1]=0.f; }
  for (int k=0;k<512;k++){
    float w0 = W[k*512 + tid];
    float w1 = W[k*512 + tid + 256];
#pragma unroll
    for (int r=0;r<4;r++){
      float s = sr[r*512 + k];
      acc[r][0] += s*w0; acc[r][1] += s*w1;
    }
  }
  float b0 = bias[tid], b1 = bias[tid + 256];
#pragma unroll
  for (int r=0;r<4;r++){
    size_t row = (size_t)(r0 + r);
    out[row*512 + tid]       = x[row*512 + tid]       + acc[r][0] + b0;
    out[row*512 + tid + 256] = x[row*512 + tid + 256] + acc[r][1] + b1;
  }
}

extern "C" void kernel_launch(void* const* d_in, const int* in_sizes, int n_in,
                              void* d_out, int out_size, void* d_ws, size_t ws_size,
                              hipStream_t stream) {
  (void)in_sizes; (void)n_in; (void)out_size; (void)ws_size;
  const float* x        = (const float*)d_in[0];
  const float* xf       = (const float*)d_in[1];
  const float* emb      = (const float*)d_in[2];
  const float* src_mask = (const float*)d_in[3];
  const float* norm_g   = (const float*)d_in[4];
  const float* norm_b   = (const float*)d_in[5];
  const float* tnorm_g  = (const float*)d_in[6];
  const float* tnorm_b  = (const float*)d_in[7];
  const float* m_pos    = (const float*)d_in[8];
  const float* m_gate   = (const float*)d_in[9];
  const float* m_fc1w   = (const float*)d_in[10];
  const float* m_fc1b   = (const float*)d_in[11];
  const float* m_fc2w   = (const float*)d_in[12];
  const float* m_fc2b   = (const float*)d_in[13];
  const float* m_projw  = (const float*)d_in[14];
  const float* m_projb  = (const float*)d_in[15];
  const float* t_pos    = (const float*)d_in[16];
  const float* t_gate   = (const float*)d_in[17];
  const float* t_fc1w   = (const float*)d_in[18];
  const float* t_fc1b   = (const float*)d_in[19];
  const float* t_fc2w   = (const float*)d_in[20];
  const float* t_fc2b   = (const float*)d_in[21];
  const float* t_projw  = (const float*)d_in[22];
  const float* t_projb  = (const float*)d_in[23];
  const float* body_w   = (const float*)d_in[24];
  const float* sb_embw  = (const float*)d_in[25];
  const float* sb_embb  = (const float*)d_in[26];
  const float* sb_ng    = (const float*)d_in[27];
  const float* sb_nb    = (const float*)d_in[28];
  const float* sb_outw  = (const float*)d_in[29];
  const float* sb_outb  = (const float*)d_in[30];
  const int*   cond     = (const int*)d_in[31];

  // workspace layout (bytes): total ~78.3 MB
  char* base = (char*)d_ws;
  bf16*  mf    = (bf16*)(base);                       // 131072*256 bf16 = 67,108,864 B
  float* tfeat = (float*)(base + 67108864);           // 4928*128 f32   =  2,523,136 B
  float* attnw = (float*)(base + 67108864 + 2523136); // 512*4096 f32   =  8,388,608 B
  float* eo    = (float*)(base + 67108864 + 2523136 + 8388608);          // 262,144 B
  float* bwv   = (float*)(base + 67108864 + 2523136 + 8388608 + 262144); // 256 B
  float* sbuf  = (float*)d_out;                       // staged in d_out, consumed in-place by k_out

  k_bw<<<1, 64, 0, stream>>>(body_w, bwv);
  k_text<<<4928, 256, 0, stream>>>(xf, tnorm_g, tnorm_b, t_pos, t_gate,
                                   t_fc1w, t_fc1b, t_fc2w, t_fc2b, t_projw, t_projb, tfeat);
  k_motion<<<131072, 64, 0, stream>>>(x, norm_g, norm_b, m_pos, m_gate,
                                      m_fc1w, m_fc1b, m_fc2w, m_fc2b, m_projw, m_projb, mf);
  k_eo<<<256, 256, 0, stream>>>(emb, sb_embw, sb_embb, eo);
  k_attn<<<512, 256, 0, stream>>>(tfeat, mf, src_mask, cond, attnw);
  k_j1<<<16384, 256, 0, stream>>>(mf, attnw, bwv, eo, sb_ng, sb_nb, sbuf);
  k_out<<<4096, 256, 0, stream>>>(sb_outw, sb_outb, x, (float*)d_out);
}

// Round 4
// 1423.028 us; speedup vs baseline: 2.4781x; 2.4781x over previous
//
#include <hip/hip_runtime.h>
#include <hip/hip_bf16.h>

// STMA block, MI355X. Round 4: expert-stationary sparse MoE GEMMs (gather),
// bf16-packed weights, transposed LDS fragments (ds_read_b128 + broadcast).
// f32 inputs/outputs; f32 accumulation everywhere.

typedef __hip_bfloat16 bf16;
typedef unsigned short u16;
typedef unsigned int   u32;

__device__ __forceinline__ float b2f(bf16 v){ return __bfloat162float(v); }
__device__ __forceinline__ u16 f2bu(float f){
  __hip_bfloat16 h = __float2bfloat16(f);
  union { __hip_bfloat16 hh; u16 us; } cv; cv.hh = h; return cv.us;
}
__device__ __forceinline__ float bu2f(u16 v){ return __uint_as_float(((u32)v)<<16); }
__device__ __forceinline__ float plo(u32 u){ return __uint_as_float(u<<16); }
__device__ __forceinline__ float phi(u32 u){ return __uint_as_float(u & 0xffff0000u); }
__device__ __forceinline__ float geluf(float x){ return 0.5f*x*(1.0f+erff(x*0.7071067811865475f)); }
__device__ __forceinline__ float siluf(float x){ return x/(1.0f+expf(-x)); }

__device__ __forceinline__ float wsum(float v){
#pragma unroll
  for (int o=32;o>0;o>>=1) v += __shfl_xor(v,o,64);
  return v;
}
__device__ __forceinline__ float wmax(float v){
#pragma unroll
  for (int o=32;o>0;o>>=1) v = fmaxf(v, __shfl_xor(v,o,64));
  return v;
}
__device__ __forceinline__ void top2(const float* lg, int& i1, int& i2, float& wA){
  i1 = 0; float v1 = lg[0];
#pragma unroll
  for (int e=1;e<8;e++) if (lg[e] > v1){ v1 = lg[e]; i1 = e; }
  i2 = 0; float v2 = -1e30f;
#pragma unroll
  for (int e=0;e<8;e++) if (e != i1 && lg[e] > v2){ v2 = lg[e]; i2 = e; }
  wA = 1.f/(1.f + expf(v2 - v1));
}
__device__ __forceinline__ void unp16(const u16* base, float* xv){
  const int4* xp = (const int4*)base;
  int4 A = xp[0], B = xp[1];
  xv[0]=plo((u32)A.x); xv[1]=phi((u32)A.x); xv[2]=plo((u32)A.y); xv[3]=phi((u32)A.y);
  xv[4]=plo((u32)A.z); xv[5]=phi((u32)A.z); xv[6]=plo((u32)A.w); xv[7]=phi((u32)A.w);
  xv[8]=plo((u32)B.x); xv[9]=phi((u32)B.x); xv[10]=plo((u32)B.y); xv[11]=phi((u32)B.y);
  xv[12]=plo((u32)B.z); xv[13]=phi((u32)B.z); xv[14]=plo((u32)B.w); xv[15]=phi((u32)B.w);
}

// ---------------- small utility kernels ----------------
__global__ __launch_bounds__(64) void k_zero(int* cnts){ cnts[threadIdx.x] = 0; }

__global__ __launch_bounds__(64) void k_bw(const float* __restrict__ body_w, float* __restrict__ bwv){
  int t = threadIdx.x;
  if (t < 8){
    float v[8]; float mx = -1e30f;
#pragma unroll
    for (int j=0;j<8;j++){ v[j] = body_w[t*8+j]; mx = fmaxf(mx, v[j]); }
    float s = 0.f;
#pragma unroll
    for (int j=0;j<8;j++){ v[j] = expf(v[j]-mx); s += v[j]; }
#pragma unroll
    for (int j=0;j<8;j++) bwv[t*8+j] = v[j]/s;
  }
}

__global__ __launch_bounds__(256) void k_conv(const float* __restrict__ s, u16* __restrict__ d, int n){
  for (int i = blockIdx.x*256 + threadIdx.x; i < n; i += gridDim.x*256) d[i] = f2bu(s[i]);
}

__global__ __launch_bounds__(256) void k_count(const int2* __restrict__ eidx, int n, int* __restrict__ cnt){
  __shared__ int h[8];
  int tid = threadIdx.x;
  if (tid < 8) h[tid] = 0;
  __syncthreads();
  for (int i = blockIdx.x*256 + tid; i < n; i += gridDim.x*256){
    int2 e = eidx[i];
    atomicAdd(&h[e.x], 1); atomicAdd(&h[e.y], 1);
  }
  __syncthreads();
  if (tid < 8) atomicAdd(&cnt[tid], h[tid]);
}

// cnts layout (ints): [0..7]=cntT [8..15]=cntM [16..23]=offT [24..31]=offM [32..39]=offT2 [40..47]=offM2
__global__ __launch_bounds__(64) void k_scan(int* cnts){
  if (threadIdx.x == 0){
    int s = 0;
    for (int e=0;e<8;e++){ cnts[16+e] = s; cnts[32+e] = s; s += cnts[e]; }
    s = 0;
    for (int e=0;e<8;e++){ cnts[24+e] = s; cnts[40+e] = s; s += cnts[8+e]; }
  }
}

__global__ __launch_bounds__(256) void k_fill(const int2* __restrict__ eidx, int n,
                                              int* __restrict__ off2, int* __restrict__ alist){
  __shared__ int lc[8], gb[8], lc2[8];
  int tid = threadIdx.x;
  if (tid < 8){ lc[tid] = 0; lc2[tid] = 0; }
  __syncthreads();
  for (int i = blockIdx.x*256 + tid; i < n; i += gridDim.x*256){
    int2 e = eidx[i];
    atomicAdd(&lc[e.x], 1); atomicAdd(&lc[e.y], 1);
  }
  __syncthreads();
  if (tid < 8) gb[tid] = atomicAdd(&off2[tid], lc[tid]);
  __syncthreads();
  for (int i = blockIdx.x*256 + tid; i < n; i += gridDim.x*256){
    int2 e = eidx[i];
    int s0 = atomicAdd(&lc2[e.x], 1); alist[gb[e.x] + s0] = i*2;
    int s1 = atomicAdd(&lc2[e.y], 1); alist[gb[e.y] + s1] = i*2 + 1;
  }
}

// ---------------- pre kernels: LN + pos + gate ----------------
__global__ __launch_bounds__(256) void k_text_pre(
    const float* __restrict__ xf, const float* __restrict__ tg, const float* __restrict__ tb,
    const float* __restrict__ tpos, const float* __restrict__ gw,
    u16* __restrict__ xtb, int2* __restrict__ eidxT, float2* __restrict__ ewT){
  int tok = blockIdx.x, tid = threadIdx.x;
  int n = tok % 77;
  __shared__ float redw[32], lgs[8];
  int w = tid >> 6, ln = tid & 63;
  float xv = xf[tok*256 + tid];
  float s1 = wsum(xv);
  if (ln == 0) redw[w] = s1;
  __syncthreads();
  float mean = (redw[0]+redw[1]+redw[2]+redw[3]) * (1.f/256.f);
  __syncthreads();
  float c = xv - mean;
  float s2 = wsum(c*c);
  if (ln == 0) redw[w] = s2;
  __syncthreads();
  float var = (redw[0]+redw[1]+redw[2]+redw[3]) * (1.f/256.f);
  float r = rsqrtf(var + 1e-5f);
  float xn = c*r*tg[tid] + tb[tid] + tpos[n*256 + tid];
  xtb[tok*256 + tid] = f2bu(xn);
  __syncthreads();   // fence redw reuse
  float lp[8];
#pragma unroll
  for (int e=0;e<8;e++) lp[e] = wsum(xn * gw[tid*8 + e]);
  if (ln == 0){
#pragma unroll
    for (int e=0;e<8;e++) redw[w*8+e] = lp[e];
  }
  __syncthreads();
  if (tid < 8) lgs[tid] = redw[tid] + redw[8+tid] + redw[16+tid] + redw[24+tid];
  __syncthreads();
  if (tid == 0){
    int i1, i2; float wA; top2(lgs, i1, i2, wA);
    eidxT[tok] = make_int2(i1, i2);
    ewT[tok] = make_float2(wA, 1.f - wA);
  }
}

__global__ __launch_bounds__(256) void k_motion_pre(
    const float* __restrict__ x, const float* __restrict__ ng, const float* __restrict__ nb,
    const float* __restrict__ mpos, const float* __restrict__ gw,
    u16* __restrict__ xmb, int2* __restrict__ eidxM, float2* __restrict__ ewM){
  int tok = blockIdx.x*4 + (threadIdx.x >> 6);
  int d = threadIdx.x & 63;
  float xv = x[(size_t)tok*64 + d];
  float m = wsum(xv) * (1.f/64.f);
  float c = xv - m;
  float var = wsum(c*c) * (1.f/64.f);
  float r = rsqrtf(var + 1e-5f);
  int h = tok & 7; int t = (tok >> 3) & 255;
  float xn = c*r*ng[d] + nb[d] + mpos[(t*8+h)*64 + d];
  xmb[(size_t)tok*64 + d] = f2bu(xn);
  float lg[8];
#pragma unroll
  for (int e=0;e<8;e++) lg[e] = wsum(xn * gw[d*8 + e]);
  if (d == 0){
    int i1, i2; float wA; top2(lg, i1, i2, wA);
    eidxM[tok] = make_int2(i1, i2);
    ewM[tok] = make_float2(wA, 1.f - wA);
  }
}

// ---------------- text expert GEMM: tile of 16 tokens of one expert ----------------
// FC1 (256->1024, gelu) fused with FC2 (1024->256). Contribution (incl fc2b, no gate) -> ycT[v].
__global__ __launch_bounds__(256) void k_text_moe(
    const u16* __restrict__ xtb, const int* __restrict__ alistT, const int* __restrict__ cnts,
    const u16* __restrict__ t1b, const float* __restrict__ fc1b,
    const u16* __restrict__ t2b, const float* __restrict__ fc2b,
    float* __restrict__ ycT){
  int e = blockIdx.y, tile = blockIdx.x, tid = threadIdx.x;
  int cnt = cnts[e];
  int base = tile*16;
  if (base >= cnt) return;
  int n = min(16, cnt - base);
  int off = cnts[16+e];
  __shared__ int toks[16];
  __shared__ u16 xsT[256*16];     // [k][t] bf16
  __shared__ float hbT[1024*16];  // [k][t] f32
  if (tid < 16) toks[tid] = alistT[off + base + (tid < n ? tid : 0)];
  __syncthreads();
#pragma unroll
  for (int i=0;i<16;i++) xsT[(size_t)tid*16 + i] = xtb[(size_t)(toks[i]>>1)*256 + tid];
  __syncthreads();
  // FC1: two passes of 512 cols (2 per thread)
  const u32* w1p = (const u32*)t1b + (size_t)e*131072;  // e*256*1024/2
#pragma unroll 1
  for (int p=0;p<2;p++){
    int c = p*512 + 2*tid;
    float a0[16], a1[16];
    float bb0 = fc1b[e*1024 + c], bb1 = fc1b[e*1024 + c + 1];
#pragma unroll
    for (int t=0;t<16;t++){ a0[t] = bb0; a1[t] = bb1; }
    for (int k=0;k<256;k++){
      u32 wv = w1p[(k*1024 + c) >> 1];
      float w0 = plo(wv), w1v = phi(wv);
      float xv[16]; unp16(xsT + k*16, xv);
#pragma unroll
      for (int t=0;t<16;t++){ a0[t] += xv[t]*w0; a1[t] += xv[t]*w1v; }
    }
#pragma unroll
    for (int t=0;t<16;t++){
      hbT[(size_t)c*16 + t]     = geluf(a0[t]);
      hbT[(size_t)(c+1)*16 + t] = geluf(a1[t]);
    }
  }
  __syncthreads();
  // FC2: one col per thread, K=1024
  int c = tid;
  float acc[16];
  float bb2 = fc2b[e*256 + c];
#pragma unroll
  for (int t=0;t<16;t++) acc[t] = bb2;
  const u16* w2p = t2b + (size_t)e*262144;
  for (int k=0;k<1024;k++){
    float wv = bu2f(w2p[k*256 + c]);
    const float4* hp = (const float4*)(hbT + (size_t)k*16);
    float4 h0 = hp[0], h1 = hp[1], h2 = hp[2], h3 = hp[3];
    acc[0]+=h0.x*wv; acc[1]+=h0.y*wv; acc[2]+=h0.z*wv; acc[3]+=h0.w*wv;
    acc[4]+=h1.x*wv; acc[5]+=h1.y*wv; acc[6]+=h1.z*wv; acc[7]+=h1.w*wv;
    acc[8]+=h2.x*wv; acc[9]+=h2.y*wv; acc[10]+=h2.z*wv; acc[11]+=h2.w*wv;
    acc[12]+=h3.x*wv; acc[13]+=h3.y*wv; acc[14]+=h3.z*wv; acc[15]+=h3.w*wv;
  }
#pragma unroll
  for (int t=0;t<16;t++)
    if (t < n) ycT[(size_t)toks[t]*256 + c] = acc[t];
}

// combine 2 expert contributions (gate-weighted), gelu, proj 256->128 -> tfeat
__global__ __launch_bounds__(128) void k_text_combine(
    const float* __restrict__ ycT, const float2* __restrict__ ewT,
    const float* __restrict__ pw, const float* __restrict__ pb,
    float* __restrict__ tfeat){
  int t = blockIdx.x, tid = threadIdx.x;
  __shared__ float gy[256];
  float2 w = ewT[t];
  for (int c=tid; c<256; c+=128){
    float y = w.x*ycT[(size_t)(t*2)*256 + c] + w.y*ycT[(size_t)(t*2+1)*256 + c];
    gy[c] = geluf(y);
  }
  __syncthreads();
  float a = pb[tid];
  for (int k=0;k<256;k++) a += gy[k] * pw[k*128 + tid];
  tfeat[(size_t)t*128 + tid] = a;
}

// ---------------- motion expert GEMM: tile of 32 tokens ----------------
__global__ __launch_bounds__(256) void k_motion_moe(
    const u16* __restrict__ xmb, const int* __restrict__ alistM, const int* __restrict__ cnts,
    const u16* __restrict__ m1b, const float* __restrict__ fc1b,
    const u16* __restrict__ m2b, const float* __restrict__ fc2b,
    u16* __restrict__ ycM){
  int e = blockIdx.y, tile = blockIdx.x, tid = threadIdx.x;
  int cnt = cnts[8+e];
  int base = tile*32;
  if (base >= cnt) return;
  int n = min(32, cnt - base);
  int off = cnts[24+e];
  __shared__ int toks[32];
  __shared__ u16 xsT[64*32];    // [k][t]
  __shared__ float hT[256*32];  // [k][t]
  if (tid < 32) toks[tid] = alistM[off + base + (tid < n ? tid : 0)];
  __syncthreads();
#pragma unroll
  for (int i=0;i<8;i++){
    int idx = tid + 256*i; int t = idx >> 6, c = idx & 63;
    xsT[c*32 + t] = xmb[(size_t)(toks[t]>>1)*64 + c];
  }
  __syncthreads();
  // FC1: 64->256. half group: 16 tokens; col pair per thread.
  {
    int half = tid >> 7, cp = tid & 127, c = 2*cp;
    float a0[16], a1[16];
    float bb0 = fc1b[e*256 + c], bb1 = fc1b[e*256 + c + 1];
#pragma unroll
    for (int t=0;t<16;t++){ a0[t] = bb0; a1[t] = bb1; }
    const u32* w1p = (const u32*)m1b + (size_t)e*8192;   // e*64*256/2
    for (int k=0;k<64;k++){
      u32 wv = w1p[(k*256 + c) >> 1];
      float w0 = plo(wv), w1v = phi(wv);
      float xv[16]; unp16(xsT + k*32 + half*16, xv);
#pragma unroll
      for (int t=0;t<16;t++){ a0[t] += xv[t]*w0; a1[t] += xv[t]*w1v; }
    }
#pragma unroll
    for (int t=0;t<16;t++){
      hT[c*32 + half*16 + t]     = geluf(a0[t]);
      hT[(c+1)*32 + half*16 + t] = geluf(a1[t]);
    }
  }
  __syncthreads();
  // FC2: 256->64. 8 token-groups x 32 col-pairs.
  {
    int tg = tid >> 5, cp = tid & 31, c = 2*cp;
    float a[4][2];
    float bb0 = fc2b[e*64 + c], bb1 = fc2b[e*64 + c + 1];
#pragma unroll
    for (int i=0;i<4;i++){ a[i][0] = bb0; a[i][1] = bb1; }
    const u32* w2p = (const u32*)m2b + (size_t)e*8192;   // e*256*64/2
    for (int k=0;k<256;k++){
      u32 wv = w2p[(k*64 + c) >> 1];
      float w0 = plo(wv), w1v = phi(wv);
      float4 h = ((const float4*)(hT + k*32 + tg*4))[0];
      a[0][0]+=h.x*w0; a[0][1]+=h.x*w1v;
      a[1][0]+=h.y*w0; a[1][1]+=h.y*w1v;
      a[2][0]+=h.z*w0; a[2][1]+=h.z*w1v;
      a[3][0]+=h.w*w0; a[3][1]+=h.w*w1v;
    }
#pragma unroll
    for (int i=0;i<4;i++){
      int t = tg*4 + i;
      if (t < n){
        u32 pk = ((u32)f2bu(a[i][1]) << 16) | (u32)f2bu(a[i][0]);
        ((u32*)ycM)[(size_t)toks[t]*32 + cp] = pk;
      }
    }
  }
}

// combine motion contributions, gelu, proj 64->256 -> mf (bf16)
__global__ __launch_bounds__(256) void k_motion_combine(
    const u16* __restrict__ ycM, const float2* __restrict__ ewM,
    const u16* __restrict__ mpb, const float* __restrict__ pbias,
    u16* __restrict__ mf){
  int t0 = blockIdx.x*16, tid = threadIdx.x;
  __shared__ float gyT[64*16];   // [k][t]
#pragma unroll
  for (int i=0;i<4;i++){
    int idx = tid + 256*i; int t = idx >> 6, c = idx & 63;
    int tok = t0 + t;
    float2 w = ewM[tok];
    float c0 = bu2f(ycM[(size_t)(tok*2)*64 + c]);
    float c1 = bu2f(ycM[(size_t)(tok*2+1)*64 + c]);
    gyT[c*16 + t] = geluf(w.x*c0 + w.y*c1);
  }
  __syncthreads();
  int c = tid;
  float acc[16];
  float bb = pbias[c];
#pragma unroll
  for (int t=0;t<16;t++) acc[t] = bb;
  for (int k=0;k<64;k++){
    float wv = bu2f(mpb[k*256 + c]);
    const float4* gp = (const float4*)(gyT + k*16);
    float4 g0 = gp[0], g1 = gp[1], g2 = gp[2], g3 = gp[3];
    acc[0]+=g0.x*wv; acc[1]+=g0.y*wv; acc[2]+=g0.z*wv; acc[3]+=g0.w*wv;
    acc[4]+=g1.x*wv; acc[5]+=g1.y*wv; acc[6]+=g1.z*wv; acc[7]+=g1.w*wv;
    acc[8]+=g2.x*wv; acc[9]+=g2.y*wv; acc[10]+=g2.z*wv; acc[11]+=g2.w*wv;
    acc[12]+=g3.x*wv; acc[13]+=g3.y*wv; acc[14]+=g3.z*wv; acc[15]+=g3.w*wv;
  }
#pragma unroll
  for (int t=0;t<16;t++) mf[(size_t)(t0+t)*256 + c] = f2bu(acc[t]);
}

// ---------------- eo = silu(emb) @ (2048x1024) + b ----------------
__global__ __launch_bounds__(256) void k_eo(const float* __restrict__ emb, const float* __restrict__ ew,
                     const float* __restrict__ ebias, float* __restrict__ eo){
  int b = blockIdx.x >> 2; int q = blockIdx.x & 3; int tid = threadIdx.x;
  __shared__ float se[2048];
#pragma unroll
  for (int i=0;i<8;i++){ int k = tid + 256*i; se[k] = siluf(emb[b*2048 + k]); }
  __syncthreads();
  int c = q*256 + tid;
  float a = ebias[c];
  for (int k=0;k<2048;k++) a += se[k] * ew[k*1024 + c];
  eo[b*1024 + c] = a;
}

// ---------------- attention (unchanged from round 3) ----------------
__global__ __launch_bounds__(256) void k_attn(const float* __restrict__ tfeat, const bf16* __restrict__ mf,
                       const float* __restrict__ src_mask, const int* __restrict__ cond,
                       float* __restrict__ attnw){
  int b = blockIdx.x >> 3; int h = blockIdx.x & 7;
  int tid = threadIdx.x; int d = tid & 63; int part = tid >> 6;
  __shared__ float colmax[64], colsum[64], red[256];
  __shared__ float kch[4096], vch[4096];
  float tc = ((cond[b] % 10) > 0) ? 1.f : 0.f;
  float negt = (1.f - tc) * (-1e6f);

  float mx = -1e30f;
  for (int n = part; n < 333; n += 4){
    float kv;
    if (n < 77){ kv = tfeat[(b*77+n)*128 + d] + negt; }
    else { int t = n - 77; float smv = src_mask[b*256 + t];
           kv = b2f(mf[((size_t)(b*256+t)*8+h)*256 + 64 + d]) + (1.f - smv)*(-1e6f); }
    mx = fmaxf(mx, kv);
  }
  red[tid] = mx; __syncthreads();
  if (part == 0) colmax[d] = fmaxf(fmaxf(red[d],red[d+64]), fmaxf(red[d+128],red[d+192]));
  __syncthreads();
  float cm = colmax[d];
  float sacc = 0.f;
  for (int n = part; n < 333; n += 4){
    float kv;
    if (n < 77){ kv = tfeat[(b*77+n)*128 + d] + negt; }
    else { int t = n - 77; float smv = src_mask[b*256 + t];
           kv = b2f(mf[((size_t)(b*256+t)*8+h)*256 + 64 + d]) + (1.f - smv)*(-1e6f); }
    sacc += expf(kv - cm);
  }
  red[tid] = sacc; __syncthreads();
  if (part == 0) colsum[d] = red[d]+red[d+64]+red[d+128]+red[d+192];
  __syncthreads();
  float acc[16];
#pragma unroll
  for (int j=0;j<16;j++) acc[j] = 0.f;
  int l0 = part*16;
  for (int nc = 0; nc < 333; nc += 64){
    int nn = (333 - nc < 64) ? (333 - nc) : 64;
    for (int idx = tid; idx < nn*64; idx += 256){
      int rr = idx >> 6; int cc = idx & 63; int n = nc + rr;
      float kv, vv;
      if (n < 77){
        const float* trow = tfeat + (b*77+n)*128;
        kv = trow[cc] + negt;
        vv = trow[64 + cc] * tc;
      } else {
        int t = n - 77; float smv = src_mask[b*256 + t];
        const bf16* mrow = mf + ((size_t)(b*256+t)*8+h)*256;
        kv = b2f(mrow[64 + cc]) + (1.f - smv)*(-1e6f);
        vv = b2f(mrow[128 + cc]) * smv;
      }
      kch[idx] = expf(kv - colmax[cc]);
      vch[idx] = vv;
    }
    __syncthreads();
    for (int rr=0; rr<nn; rr++){
      float e = kch[rr*64 + d];
      const float* vrow = vch + rr*64 + l0;
#pragma unroll
      for (int j=0;j<16;j++) acc[j] += e * vrow[j];
    }
    __syncthreads();
  }
  float inv = 1.f / colsum[d];
  float* outp = attnw + ((size_t)(b*8+h)*64 + d)*64 + l0;
#pragma unroll
  for (int j=0;j<16;j++) outp[j] = acc[j] * inv;
}

// ---------------- j1 (unchanged from round 3) ----------------
__global__ __launch_bounds__(256) void k_j1(const bf16* __restrict__ mf, const float* __restrict__ attnw,
                     const float* __restrict__ bwv, const float* __restrict__ eo,
                     const float* __restrict__ sb_ng, const float* __restrict__ sb_nb,
                     float* __restrict__ sbuf){
  int blk = blockIdx.x; int b = blk >> 8; int t = blk & 255;
  int tid = threadIdx.x;
  __shared__ float q[512], mfl[512], red[4];
#pragma unroll
  for (int ii=0; ii<2; ii++){
    int idx = tid + ii*256; int h = idx >> 6; int dd = idx & 63;
    const bf16* mrow = mf + ((size_t)(b*256+t)*8+h)*256;
    q[idx]   = b2f(mrow[192 + dd]);
    mfl[idx] = b2f(mrow[dd]);
  }
  __syncthreads();
  int w = tid >> 6, ln = tid & 63;
  for (int h = w; h < 8; h += 4){
    float v = q[h*64 + ln];
    float mx = wmax(v);
    float e = expf(v - mx);
    float s = wsum(e);
    q[h*64 + ln] = e/s;
  }
  __syncthreads();
  float out[2];
#pragma unroll
  for (int ii=0; ii<2; ii++){
    int idx = tid + ii*256; int h = idx >> 6; int l = idx & 63;
    float a = 0.f;
    const float* ap = attnw + (size_t)(b*8+h)*4096 + l;
    for (int dd=0; dd<64; dd++) a += q[h*64 + dd] * ap[dd*64];
    float bs = 0.f;
#pragma unroll
    for (int lh=0; lh<8; lh++) bs += bwv[h*8 + lh] * mfl[lh*64 + l];
    out[ii] = a + bs;
  }
  float psum = wsum(out[0] + out[1]);
  if (ln == 0) red[w] = psum;
  __syncthreads();
  float mean = (red[0]+red[1]+red[2]+red[3]) * (1.f/512.f);
  __syncthreads();
  float c0 = out[0]-mean, c1 = out[1]-mean;
  float pv = wsum(c0*c0 + c1*c1);
  if (ln == 0) red[w] = pv;
  __syncthreads();
  float var = (red[0]+red[1]+red[2]+red[3]) * (1.f/512.f);
  float r = rsqrtf(var + 1e-5f);
#pragma unroll
  for (int ii=0; ii<2; ii++){
    int c = tid + ii*256;
    float hn = (out[ii]-mean)*r*sb_ng[c] + sb_nb[c];
    float e1 = eo[b*1024 + c], e2 = eo[b*1024 + 512 + c];
    float hm = hn*(1.f + e1) + e2;
    sbuf[(size_t)blk*512 + c] = siluf(hm);
  }
}

// ---------------- out = x + sbuf @ W(bf16) + b ----------------
__global__ __launch_bounds__(256) void k_out(const u16* __restrict__ Wb,
                      const float* __restrict__ bias, const float* __restrict__ x,
                      float* __restrict__ out){
  int r0 = blockIdx.x * 4; int tid = threadIdx.x;
  __shared__ float sr[4*512];
#pragma unroll
  for (int i=0;i<8;i++){ int idx = tid + 256*i; sr[idx] = out[(size_t)r0*512 + idx]; }
  __syncthreads();
  float acc[4][2];
#pragma unroll
  for (int r=0;r<4;r++){ acc[r][0]=0.f; acc[r][1]=0.f; }
  const u32* wp = (const u32*)Wb;
  for (int k=0;k<512;k++){
    u32 wv = wp[k*256 + tid];
    float w0 = plo(wv), w1v = phi(wv);
#pragma unroll
    for (int r=0;r<4;r++){
      float s = sr[r*512 + k];
      acc[r][0] += s*w0; acc[r][1] += s*w1v;
    }
  }
  float b0 = bias[2*tid], b1 = bias[2*tid + 1];
#pragma unroll
  for (int r=0;r<4;r++){
    size_t row = (size_t)(r0 + r);
    float2 xv = ((const float2*)x)[row*256 + tid];
    float2 ov; ov.x = xv.x + acc[r][0] + b0; ov.y = xv.y + acc[r][1] + b1;
    ((float2*)out)[row*256 + tid] = ov;
  }
}

extern "C" void kernel_launch(void* const* d_in, const int* in_sizes, int n_in,
                              void* d_out, int out_size, void* d_ws, size_t ws_size,
                              hipStream_t stream) {
  (void)in_sizes; (void)n_in; (void)out_size; (void)ws_size;
  const float* x        = (const float*)d_in[0];
  const float* xf       = (const float*)d_in[1];
  const float* emb      = (const float*)d_in[2];
  const float* src_mask = (const float*)d_in[3];
  const float* norm_g   = (const float*)d_in[4];
  const float* norm_b   = (const float*)d_in[5];
  const float* tnorm_g  = (const float*)d_in[6];
  const float* tnorm_b  = (const float*)d_in[7];
  const float* m_pos    = (const float*)d_in[8];
  const float* m_gate   = (const float*)d_in[9];
  const float* m_fc1w   = (const float*)d_in[10];
  const float* m_fc1b   = (const float*)d_in[11];
  const float* m_fc2w   = (const float*)d_in[12];
  const float* m_fc2b   = (const float*)d_in[13];
  const float* m_projw  = (const float*)d_in[14];
  const float* m_projb  = (const float*)d_in[15];
  const float* t_pos    = (const float*)d_in[16];
  const float* t_gate   = (const float*)d_in[17];
  const float* t_fc1w   = (const float*)d_in[18];
  const float* t_fc1b   = (const float*)d_in[19];
  const float* t_fc2w   = (const float*)d_in[20];
  const float* t_fc2b   = (const float*)d_in[21];
  const float* t_projw  = (const float*)d_in[22];
  const float* t_projb  = (const float*)d_in[23];
  const float* body_w   = (const float*)d_in[24];
  const float* sb_embw  = (const float*)d_in[25];
  const float* sb_embb  = (const float*)d_in[26];
  const float* sb_ng    = (const float*)d_in[27];
  const float* sb_nb    = (const float*)d_in[28];
  const float* sb_outw  = (const float*)d_in[29];
  const float* sb_outb  = (const float*)d_in[30];
  const int*   cond     = (const int*)d_in[31];

  // ---- workspace bump allocator (~133 MB), with manual lifetime aliasing ----
  char* base = (char*)d_ws;
  size_t o = 0;
  auto alloc = [&](size_t bytes)->char*{ char* r = base + o; o += (bytes + 255) & ~(size_t)255; return r; };
  u16*  mf      = (u16*)alloc(67108864);          // motion_feat bf16, live to end
  char* R       = alloc(33554432);                // aliased region
  u16*  xtb     = (u16*)(R);                      // text LN+pos bf16 [4928x256], dead after k_text_moe
  float* ycT    = (float*)(R + 4194304);          // text contributions [9856x256] f32, dead after k_text_combine
  u16*  ycM     = (u16*)(R);                      // motion contributions [262144x64] bf16, dead after k_motion_combine
  float* attnw  = (float*)(R);                    // [512x4096] f32, written after ycM dead
  u16*  xmb     = (u16*)alloc(16777216);          // motion LN+pos bf16 [131072x64]
  u16*  t1b     = (u16*)alloc(4194304);           // bf16 weights
  u16*  t2b     = (u16*)alloc(4194304);
  u16*  m1b     = (u16*)alloc(262144);
  u16*  m2b     = (u16*)alloc(262144);
  u16*  mpb     = (u16*)alloc(32768);
  u16*  owb     = (u16*)alloc(524288);
  int2* eidxT   = (int2*)alloc(39424);
  float2* ewT   = (float2*)alloc(39424);
  int2* eidxM   = (int2*)alloc(1048576);
  float2* ewM   = (float2*)alloc(1048576);
  int*  alistT  = (int*)alloc(39424);
  int*  alistM  = (int*)alloc(1048576);
  int*  cnts    = (int*)alloc(256);               // 64 ints
  float* tfeat  = (float*)alloc(2523136);
  float* eo     = (float*)alloc(262144);
  float* bwv    = (float*)alloc(256);
  float* sbuf   = (float*)d_out;

  // setup
  k_zero<<<1, 64, 0, stream>>>(cnts);
  k_bw<<<1, 64, 0, stream>>>(body_w, bwv);
  k_conv<<<512, 256, 0, stream>>>(t_fc1w, t1b, 2097152);
  k_conv<<<512, 256, 0, stream>>>(t_fc2w, t2b, 2097152);
  k_conv<<<128, 256, 0, stream>>>(m_fc1w, m1b, 131072);
  k_conv<<<128, 256, 0, stream>>>(m_fc2w, m2b, 131072);
  k_conv<<<64, 256, 0, stream>>>(m_projw, mpb, 16384);
  k_conv<<<256, 256, 0, stream>>>(sb_outw, owb, 262144);
  k_eo<<<256, 256, 0, stream>>>(emb, sb_embw, sb_embb, eo);

  // pre + routing
  k_text_pre<<<4928, 256, 0, stream>>>(xf, tnorm_g, tnorm_b, t_pos, t_gate, xtb, eidxT, ewT);
  k_motion_pre<<<32768, 256, 0, stream>>>(x, norm_g, norm_b, m_pos, m_gate, xmb, eidxM, ewM);
  k_count<<<32, 256, 0, stream>>>(eidxT, 4928, cnts);
  k_count<<<256, 256, 0, stream>>>(eidxM, 131072, cnts + 8);
  k_scan<<<1, 64, 0, stream>>>(cnts);
  k_fill<<<32, 256, 0, stream>>>(eidxT, 4928, cnts + 32, alistT);
  k_fill<<<256, 256, 0, stream>>>(eidxM, 131072, cnts + 40, alistM);

  // text MoE
  k_text_moe<<<dim3(308, 8), 256, 0, stream>>>(xtb, alistT, cnts, t1b, t_fc1b, t2b, t_fc2b, ycT);
  k_text_combine<<<4928, 128, 0, stream>>>(ycT, ewT, t_projw, t_projb, tfeat);

  // motion MoE
  k_motion_moe<<<dim3(4096, 8), 256, 0, stream>>>(xmb, alistM, cnts, m1b, m_fc1b, m2b, m_fc2b, ycM);
  k_motion_combine<<<8192, 256, 0, stream>>>(ycM, ewM, mpb, m_projb, mf);

  // attention + epilogue
  k_attn<<<512, 256, 0, stream>>>(tfeat, (const bf16*)mf, src_mask, cond, attnw);
  k_j1<<<16384, 256, 0, stream>>>((const bf16*)mf, attnw, bwv, eo, sb_ng, sb_nb, sbuf);
  k_out<<<4096, 256, 0, stream>>>(owb, sb_outb, x, (float*)d_out);
}

// Round 5
// 749.158 us; speedup vs baseline: 4.7071x; 1.8995x over previous
//
#include <hip/hip_runtime.h>
#include <hip/hip_bf16.h>

// STMA block, MI355X. Round 5: MFMA 16x16x32 bf16 for all GEMM stages
// (MoE FC1/FC2 text+motion, motion combine+proj, out-proj). Weights repacked
// on device into B-fragment order. f32 in/out, f32 accumulation.

typedef __hip_bfloat16 bf16;
typedef unsigned short u16;
typedef unsigned int   u32;
typedef __attribute__((ext_vector_type(8))) short short8;   // 8 bf16 = 4 VGPR
typedef __attribute__((ext_vector_type(4))) float f32x4;    // MFMA C/D

#define MFMA16(a,b,c) __builtin_amdgcn_mfma_f32_16x16x32_bf16(a,b,c,0,0,0)

__device__ __forceinline__ float b2f(bf16 v){ return __bfloat162float(v); }
__device__ __forceinline__ u16 f2bu(float f){
  union { __hip_bfloat16 hh; u16 us; } cv; cv.hh = __float2bfloat16(f); return cv.us;
}
__device__ __forceinline__ float bu2f(u16 v){ return __uint_as_float(((u32)v)<<16); }
__device__ __forceinline__ float geluf(float x){ return 0.5f*x*(1.0f+erff(x*0.7071067811865475f)); }
__device__ __forceinline__ float siluf(float x){ return x/(1.0f+expf(-x)); }

__device__ __forceinline__ float wsum(float v){
#pragma unroll
  for (int o=32;o>0;o>>=1) v += __shfl_xor(v,o,64);
  return v;
}
__device__ __forceinline__ float wmax(float v){
#pragma unroll
  for (int o=32;o>0;o>>=1) v = fmaxf(v, __shfl_xor(v,o,64));
  return v;
}
__device__ __forceinline__ void top2(const float* lg, int& i1, int& i2, float& wA){
  i1 = 0; float v1 = lg[0];
#pragma unroll
  for (int e=1;e<8;e++) if (lg[e] > v1){ v1 = lg[e]; i1 = e; }
  i2 = 0; float v2 = -1e30f;
#pragma unroll
  for (int e=0;e<8;e++) if (e != i1 && lg[e] > v2){ v2 = lg[e]; i2 = e; }
  wA = 1.f/(1.f + expf(v2 - v1));
}

// ---------------- utility kernels ----------------
__global__ __launch_bounds__(64) void k_zero(int* cnts){ cnts[threadIdx.x] = 0; }

__global__ __launch_bounds__(64) void k_bw(const float* __restrict__ body_w, float* __restrict__ bwv){
  int t = threadIdx.x;
  if (t < 8){
    float v[8]; float mx = -1e30f;
#pragma unroll
    for (int j=0;j<8;j++){ v[j] = body_w[t*8+j]; mx = fmaxf(mx, v[j]); }
    float s = 0.f;
#pragma unroll
    for (int j=0;j<8;j++){ v[j] = expf(v[j]-mx); s += v[j]; }
#pragma unroll
    for (int j=0;j<8;j++) bwv[t*8+j] = v[j]/s;
  }
}

// repack K x N weight (k-major, E experts) into B-fragment order, bf16.
// dest u16 idx = e*K*N + (((nt*KC + kc)*4 + q)*16 + n)*8 + j ;  k = kc*32+q*8+j
__global__ __launch_bounds__(256) void k_repack(const float* __restrict__ s, u16* __restrict__ d,
                                                int KC, int N, int total){
  int NT = N >> 4;
  for (int t = blockIdx.x*256 + threadIdx.x; t < total; t += gridDim.x*256){
    int j = t & 7, n = (t>>3) & 15, q = (t>>7) & 3;
    int r2 = t >> 9;
    int kc = r2 % KC; int r3 = r2 / KC;
    int nt = r3 % NT; int e = r3 / NT;
    int k = kc*32 + q*8 + j;
    d[t] = f2bu(s[((size_t)(e*(KC*32) + k))*N + nt*16 + n]);
  }
}

__global__ __launch_bounds__(256) void k_count(const int2* __restrict__ eidx, int n, int* __restrict__ cnt){
  __shared__ int h[8];
  int tid = threadIdx.x;
  if (tid < 8) h[tid] = 0;
  __syncthreads();
  for (int i = blockIdx.x*256 + tid; i < n; i += gridDim.x*256){
    int2 e = eidx[i];
    atomicAdd(&h[e.x], 1); atomicAdd(&h[e.y], 1);
  }
  __syncthreads();
  if (tid < 8) atomicAdd(&cnt[tid], h[tid]);
}

// cnts: [0..7]=cntT [8..15]=cntM [16..23]=offT [24..31]=offM [32..39]=offT2 [40..47]=offM2
__global__ __launch_bounds__(64) void k_scan(int* cnts){
  if (threadIdx.x == 0){
    int s = 0;
    for (int e=0;e<8;e++){ cnts[16+e] = s; cnts[32+e] = s; s += cnts[e]; }
    s = 0;
    for (int e=0;e<8;e++){ cnts[24+e] = s; cnts[40+e] = s; s += cnts[8+e]; }
  }
}

__global__ __launch_bounds__(256) void k_fill(const int2* __restrict__ eidx, int n,
                                              int* __restrict__ off2, int* __restrict__ alist){
  __shared__ int lc[8], gb[8], lc2[8];
  int tid = threadIdx.x;
  if (tid < 8){ lc[tid] = 0; lc2[tid] = 0; }
  __syncthreads();
  for (int i = blockIdx.x*256 + tid; i < n; i += gridDim.x*256){
    int2 e = eidx[i];
    atomicAdd(&lc[e.x], 1); atomicAdd(&lc[e.y], 1);
  }
  __syncthreads();
  if (tid < 8) gb[tid] = atomicAdd(&off2[tid], lc[tid]);
  __syncthreads();
  for (int i = blockIdx.x*256 + tid; i < n; i += gridDim.x*256){
    int2 e = eidx[i];
    int s0 = atomicAdd(&lc2[e.x], 1); alist[gb[e.x] + s0] = i*2;
    int s1 = atomicAdd(&lc2[e.y], 1); alist[gb[e.y] + s1] = i*2 + 1;
  }
}

// ---------------- pre: LN + pos + gate ----------------
__global__ __launch_bounds__(256) void k_text_pre(
    const float* __restrict__ xf, const float* __restrict__ tg, const float* __restrict__ tb,
    const float* __restrict__ tpos, const float* __restrict__ gw,
    u16* __restrict__ xtb, int2* __restrict__ eidxT, float2* __restrict__ ewT){
  int tok = blockIdx.x, tid = threadIdx.x;
  int n = tok % 77;
  __shared__ float redw[32], lgs[8];
  int w = tid >> 6, ln = tid & 63;
  float xv = xf[tok*256 + tid];
  float s1 = wsum(xv);
  if (ln == 0) redw[w] = s1;
  __syncthreads();
  float mean = (redw[0]+redw[1]+redw[2]+redw[3]) * (1.f/256.f);
  __syncthreads();
  float c = xv - mean;
  float s2 = wsum(c*c);
  if (ln == 0) redw[w] = s2;
  __syncthreads();
  float var = (redw[0]+redw[1]+redw[2]+redw[3]) * (1.f/256.f);
  float r = rsqrtf(var + 1e-5f);
  float xn = c*r*tg[tid] + tb[tid] + tpos[n*256 + tid];
  xtb[tok*256 + tid] = f2bu(xn);
  __syncthreads();
  float lp[8];
#pragma unroll
  for (int e=0;e<8;e++) lp[e] = wsum(xn * gw[tid*8 + e]);
  if (ln == 0){
#pragma unroll
    for (int e=0;e<8;e++) redw[w*8+e] = lp[e];
  }
  __syncthreads();
  if (tid < 8) lgs[tid] = redw[tid] + redw[8+tid] + redw[16+tid] + redw[24+tid];
  __syncthreads();
  if (tid == 0){
    int i1, i2; float wA; top2(lgs, i1, i2, wA);
    eidxT[tok] = make_int2(i1, i2);
    ewT[tok] = make_float2(wA, 1.f - wA);
  }
}

__global__ __launch_bounds__(256) void k_motion_pre(
    const float* __restrict__ x, const float* __restrict__ ng, const float* __restrict__ nb,
    const float* __restrict__ mpos, const float* __restrict__ gw,
    u16* __restrict__ xmb, int2* __restrict__ eidxM, float2* __restrict__ ewM){
  int tok = blockIdx.x*4 + (threadIdx.x >> 6);
  int d = threadIdx.x & 63;
  float xv = x[(size_t)tok*64 + d];
  float m = wsum(xv) * (1.f/64.f);
  float c = xv - m;
  float var = wsum(c*c) * (1.f/64.f);
  float r = rsqrtf(var + 1e-5f);
  int h = tok & 7; int t = (tok >> 3) & 255;
  float xn = c*r*ng[d] + nb[d] + mpos[(t*8+h)*64 + d];
  xmb[(size_t)tok*64 + d] = f2bu(xn);
  float lg[8];
#pragma unroll
  for (int e=0;e<8;e++) lg[e] = wsum(xn * gw[d*8 + e]);
  if (d == 0){
    int i1, i2; float wA; top2(lg, i1, i2, wA);
    eidxM[tok] = make_int2(i1, i2);
    ewM[tok] = make_float2(wA, 1.f - wA);
  }
}

// ---------------- motion MoE (MFMA): 32-token tiles ----------------
__global__ __launch_bounds__(256) void k_motion_moe(
    const u16* __restrict__ xmb, const int* __restrict__ alistM, const int* __restrict__ cnts,
    const u16* __restrict__ w1pk, const float* __restrict__ fc1b,
    const u16* __restrict__ w2pk, const float* __restrict__ fc2b,
    u16* __restrict__ ycM){
  int e = blockIdx.y, tile = blockIdx.x, tid = threadIdx.x;
  int cnt = cnts[8+e]; int base = tile*32;
  if (base >= cnt) return;
  int nn = min(32, cnt - base); int off = cnts[24+e];
  __shared__ int toks[32];
  __shared__ u16 xs[32*72];    // [tok][k], stride 72
  __shared__ u16 hT[32*264];   // [tok][hcol], stride 264
  if (tid < 32) toks[tid] = alistM[off + base + min(tid, nn-1)];
  __syncthreads();
  { int row = tid >> 3, c0 = (tid & 7)*8;
    short8 v = *(const short8*)(xmb + (size_t)(toks[row]>>1)*64 + c0);
    *(short8*)&xs[row*72 + c0] = v; }
  __syncthreads();
  int lane = tid & 63, w = tid >> 6;
  int n = lane & 15, q = lane >> 4;
  int mt = w & 1;
  // FC1: 64 -> 256
  short8 a0 = *(const short8*)&xs[(mt*16 + n)*72 + q*8];
  short8 a1 = *(const short8*)&xs[(mt*16 + n)*72 + 32 + q*8];
  const short8* b1 = (const short8*)(w1pk + (size_t)e*16384);
#pragma unroll
  for (int i=0;i<8;i++){
    int nt = (w>>1)*8 + i;
    f32x4 acc = {0.f,0.f,0.f,0.f};
    acc = MFMA16(a0, b1[(nt*2+0)*64 + lane], acc);
    acc = MFMA16(a1, b1[(nt*2+1)*64 + lane], acc);
    float bias = fc1b[e*256 + nt*16 + n];
#pragma unroll
    for (int r=0;r<4;r++)
      hT[(mt*16 + q*4 + r)*264 + nt*16 + n] = f2bu(geluf(acc[r] + bias));
  }
  __syncthreads();
  // FC2: 256 -> 64
  short8 a2[8];
#pragma unroll
  for (int kc=0;kc<8;kc++) a2[kc] = *(const short8*)&hT[(mt*16 + n)*264 + kc*32 + q*8];
  const short8* b2 = (const short8*)(w2pk + (size_t)e*16384);
#pragma unroll
  for (int i=0;i<2;i++){
    int nt = (w>>1)*2 + i;
    f32x4 acc = {0.f,0.f,0.f,0.f};
#pragma unroll
    for (int kc=0;kc<8;kc++) acc = MFMA16(a2[kc], b2[(nt*8+kc)*64 + lane], acc);
    float bias = fc2b[e*64 + nt*16 + n];
#pragma unroll
    for (int r=0;r<4;r++){
      int row = mt*16 + q*4 + r;
      if (row < nn) ycM[(size_t)toks[row]*64 + nt*16 + n] = f2bu(acc[r] + bias);
    }
  }
}

// ---------------- text MoE (MFMA): 16-token tiles ----------------
__global__ __launch_bounds__(256) void k_text_moe(
    const u16* __restrict__ xtb, const int* __restrict__ alistT, const int* __restrict__ cnts,
    const u16* __restrict__ w1pk, const float* __restrict__ fc1b,
    const u16* __restrict__ w2pk, const float* __restrict__ fc2b,
    float* __restrict__ ycT){
  int e = blockIdx.y, tile = blockIdx.x, tid = threadIdx.x;
  int cnt = cnts[e]; int base = tile*16;
  if (base >= cnt) return;
  int nn = min(16, cnt - base); int off = cnts[16+e];
  __shared__ int toks[16];
  __shared__ u16 xs[16*264];    // [tok][k], stride 264
  __shared__ u16 hT[16*1032];   // [tok][hcol], stride 1032
  if (tid < 16) toks[tid] = alistT[off + base + min(tid, nn-1)];
  __syncthreads();
  { int row = tid >> 4, c0 = (tid & 15)*16;
    const short8* sp = (const short8*)(xtb + (size_t)(toks[row]>>1)*256 + c0);
    short8 v0 = sp[0], v1 = sp[1];
    *(short8*)&xs[row*264 + c0] = v0;
    *(short8*)&xs[row*264 + c0 + 8] = v1; }
  __syncthreads();
  int lane = tid & 63, w = tid >> 6;
  int n = lane & 15, q = lane >> 4;
  // FC1: 256 -> 1024
  short8 a_[8];
#pragma unroll
  for (int kc=0;kc<8;kc++) a_[kc] = *(const short8*)&xs[n*264 + kc*32 + q*8];
  const short8* b1 = (const short8*)(w1pk + (size_t)e*262144);
#pragma unroll 1
  for (int i=0;i<16;i++){
    int nt = w*16 + i;
    f32x4 acc = {0.f,0.f,0.f,0.f};
#pragma unroll
    for (int kc=0;kc<8;kc++) acc = MFMA16(a_[kc], b1[(nt*8+kc)*64 + lane], acc);
    float bias = fc1b[e*1024 + nt*16 + n];
#pragma unroll
    for (int r=0;r<4;r++)
      hT[(q*4 + r)*1032 + nt*16 + n] = f2bu(geluf(acc[r] + bias));
  }
  __syncthreads();
  // FC2: 1024 -> 256
  const short8* b2 = (const short8*)(w2pk + (size_t)e*262144);
  f32x4 acc[4];
#pragma unroll
  for (int i=0;i<4;i++) acc[i] = (f32x4){0.f,0.f,0.f,0.f};
#pragma unroll 1
  for (int kc=0;kc<32;kc++){
    short8 a = *(const short8*)&hT[n*1032 + kc*32 + q*8];
#pragma unroll
    for (int i=0;i<4;i++){
      int nt = w*4 + i;
      acc[i] = MFMA16(a, b2[(nt*32+kc)*64 + lane], acc[i]);
    }
  }
#pragma unroll
  for (int i=0;i<4;i++){
    int nt = w*4 + i;
    float bias = fc2b[e*256 + nt*16 + n];
#pragma unroll
    for (int r=0;r<4;r++){
      int row = q*4 + r;
      if (row < nn) ycT[(size_t)toks[row]*256 + nt*16 + n] = acc[i][r] + bias;
    }
  }
}

// combine 2 expert contributions (gate-weighted), gelu, proj 256->128 -> tfeat
__global__ __launch_bounds__(128) void k_text_combine(
    const float* __restrict__ ycT, const float2* __restrict__ ewT,
    const float* __restrict__ pw, const float* __restrict__ pb,
    float* __restrict__ tfeat){
  int t = blockIdx.x, tid = threadIdx.x;
  __shared__ float gy[256];
  float2 w = ewT[t];
  for (int c=tid; c<256; c+=128){
    float y = w.x*ycT[(size_t)(t*2)*256 + c] + w.y*ycT[(size_t)(t*2+1)*256 + c];
    gy[c] = geluf(y);
  }
  __syncthreads();
  float a = pb[tid];
  for (int k=0;k<256;k++) a += gy[k] * pw[k*128 + tid];
  tfeat[(size_t)t*128 + tid] = a;
}

// motion combine + gelu + proj 64->256 (MFMA, dense 32-token tiles) -> mf bf16
__global__ __launch_bounds__(256) void k_mproj(
    const u16* __restrict__ ycM, const float2* __restrict__ ewM,
    const u16* __restrict__ wpk, const float* __restrict__ pb,
    u16* __restrict__ mf){
  int t0 = blockIdx.x*32, tid = threadIdx.x;
  __shared__ u16 xs[32*72];
  { int row = tid >> 3, c0 = (tid & 7)*8;
    int tok = t0 + row;
    float2 wgt = ewM[tok];
    short8 v0 = *(const short8*)(ycM + (size_t)(tok*2)*64 + c0);
    short8 v1 = *(const short8*)(ycM + (size_t)(tok*2+1)*64 + c0);
    short8 o;
#pragma unroll
    for (int j=0;j<8;j++)
      o[j] = (short)f2bu(geluf(wgt.x*bu2f((u16)v0[j]) + wgt.y*bu2f((u16)v1[j])));
    *(short8*)&xs[row*72 + c0] = o; }
  __syncthreads();
  int lane = tid & 63, w = tid >> 6;
  int n = lane & 15, q = lane >> 4;
  int mt = w & 1;
  short8 a0 = *(const short8*)&xs[(mt*16 + n)*72 + q*8];
  short8 a1 = *(const short8*)&xs[(mt*16 + n)*72 + 32 + q*8];
  const short8* bp = (const short8*)wpk;
#pragma unroll
  for (int i=0;i<8;i++){
    int nt = (w>>1)*8 + i;
    f32x4 acc = {0.f,0.f,0.f,0.f};
    acc = MFMA16(a0, bp[(nt*2+0)*64 + lane], acc);
    acc = MFMA16(a1, bp[(nt*2+1)*64 + lane], acc);
    float bias = pb[nt*16 + n];
#pragma unroll
    for (int r=0;r<4;r++){
      int tok = t0 + mt*16 + q*4 + r;
      mf[(size_t)tok*256 + nt*16 + n] = f2bu(acc[r] + bias);
    }
  }
}

// ---------------- eo = silu(emb) @ (2048x1024) + b ----------------
__global__ __launch_bounds__(256) void k_eo(const float* __restrict__ emb, const float* __restrict__ ew,
                     const float* __restrict__ ebias, float* __restrict__ eo){
  int b = blockIdx.x >> 2; int q = blockIdx.x & 3; int tid = threadIdx.x;
  __shared__ float se[2048];
#pragma unroll
  for (int i=0;i<8;i++){ int k = tid + 256*i; se[k] = siluf(emb[b*2048 + k]); }
  __syncthreads();
  int c = q*256 + tid;
  float a = ebias[c];
  for (int k=0;k<2048;k++) a += se[k] * ew[k*1024 + c];
  eo[b*1024 + c] = a;
}

// ---------------- attention ----------------
__global__ __launch_bounds__(256) void k_attn(const float* __restrict__ tfeat, const bf16* __restrict__ mf,
                       const float* __restrict__ src_mask, const int* __restrict__ cond,
                       float* __restrict__ attnw){
  int b = blockIdx.x >> 3; int h = blockIdx.x & 7;
  int tid = threadIdx.x; int d = tid & 63; int part = tid >> 6;
  __shared__ float colmax[64], colsum[64], red[256];
  __shared__ float kch[4096], vch[4096];
  float tc = ((cond[b] % 10) > 0) ? 1.f : 0.f;
  float negt = (1.f - tc) * (-1e6f);

  float mx = -1e30f;
  for (int n = part; n < 333; n += 4){
    float kv;
    if (n < 77){ kv = tfeat[(b*77+n)*128 + d] + negt; }
    else { int t = n - 77; float smv = src_mask[b*256 + t];
           kv = b2f(mf[((size_t)(b*256+t)*8+h)*256 + 64 + d]) + (1.f - smv)*(-1e6f); }
    mx = fmaxf(mx, kv);
  }
  red[tid] = mx; __syncthreads();
  if (part == 0) colmax[d] = fmaxf(fmaxf(red[d],red[d+64]), fmaxf(red[d+128],red[d+192]));
  __syncthreads();
  float cm = colmax[d];
  float sacc = 0.f;
  for (int n = part; n < 333; n += 4){
    float kv;
    if (n < 77){ kv = tfeat[(b*77+n)*128 + d] + negt; }
    else { int t = n - 77; float smv = src_mask[b*256 + t];
           kv = b2f(mf[((size_t)(b*256+t)*8+h)*256 + 64 + d]) + (1.f - smv)*(-1e6f); }
    sacc += expf(kv - cm);
  }
  red[tid] = sacc; __syncthreads();
  if (part == 0) colsum[d] = red[d]+red[d+64]+red[d+128]+red[d+192];
  __syncthreads();
  float acc[16];
#pragma unroll
  for (int j=0;j<16;j++) acc[j] = 0.f;
  int l0 = part*16;
  for (int nc = 0; nc < 333; nc += 64){
    int nn = (333 - nc < 64) ? (333 - nc) : 64;
    for (int idx = tid; idx < nn*64; idx += 256){
      int rr = idx >> 6; int cc = idx & 63; int n = nc + rr;
      float kv, vv;
      if (n < 77){
        const float* trow = tfeat + (b*77+n)*128;
        kv = trow[cc] + negt;
        vv = trow[64 + cc] * tc;
      } else {
        int t = n - 77; float smv = src_mask[b*256 + t];
        const bf16* mrow = mf + ((size_t)(b*256+t)*8+h)*256;
        kv = b2f(mrow[64 + cc]) + (1.f - smv)*(-1e6f);
        vv = b2f(mrow[128 + cc]) * smv;
      }
      kch[idx] = expf(kv - colmax[cc]);
      vch[idx] = vv;
    }
    __syncthreads();
    for (int rr=0; rr<nn; rr++){
      float e = kch[rr*64 + d];
      const float* vrow = vch + rr*64 + l0;
#pragma unroll
      for (int j=0;j<16;j++) acc[j] += e * vrow[j];
    }
    __syncthreads();
  }
  float inv = 1.f / colsum[d];
  float* outp = attnw + ((size_t)(b*8+h)*64 + d)*64 + l0;
#pragma unroll
  for (int j=0;j<16;j++) outp[j] = acc[j] * inv;
}

// ---------------- j1: q-softmax, y_t, body mix, LN, modulate, silu -> sbuf ----------------
__global__ __launch_bounds__(256) void k_j1(const bf16* __restrict__ mf, const float* __restrict__ attnw,
                     const float* __restrict__ bwv, const float* __restrict__ eo,
                     const float* __restrict__ sb_ng, const float* __restrict__ sb_nb,
                     float* __restrict__ sbuf){
  int blk = blockIdx.x; int b = blk >> 8; int t = blk & 255;
  int tid = threadIdx.x;
  __shared__ float q[512], mfl[512], red[4];
#pragma unroll
  for (int ii=0; ii<2; ii++){
    int idx = tid + ii*256; int h = idx >> 6; int dd = idx & 63;
    const bf16* mrow = mf + ((size_t)(b*256+t)*8+h)*256;
    q[idx]   = b2f(mrow[192 + dd]);
    mfl[idx] = b2f(mrow[dd]);
  }
  __syncthreads();
  int w = tid >> 6, ln = tid & 63;
  for (int h = w; h < 8; h += 4){
    float v = q[h*64 + ln];
    float mx = wmax(v);
    float e = expf(v - mx);
    float s = wsum(e);
    q[h*64 + ln] = e/s;
  }
  __syncthreads();
  float out[2];
#pragma unroll
  for (int ii=0; ii<2; ii++){
    int idx = tid + ii*256; int h = idx >> 6; int l = idx & 63;
    float a = 0.f;
    const float* ap = attnw + (size_t)(b*8+h)*4096 + l;
    for (int dd=0; dd<64; dd++) a += q[h*64 + dd] * ap[dd*64];
    float bs = 0.f;
#pragma unroll
    for (int lh=0; lh<8; lh++) bs += bwv[h*8 + lh] * mfl[lh*64 + l];
    out[ii] = a + bs;
  }
  float psum = wsum(out[0] + out[1]);
  if (ln == 0) red[w] = psum;
  __syncthreads();
  float mean = (red[0]+red[1]+red[2]+red[3]) * (1.f/512.f);
  __syncthreads();
  float c0 = out[0]-mean, c1 = out[1]-mean;
  float pv = wsum(c0*c0 + c1*c1);
  if (ln == 0) red[w] = pv;
  __syncthreads();
  float var = (red[0]+red[1]+red[2]+red[3]) * (1.f/512.f);
  float r = rsqrtf(var + 1e-5f);
#pragma unroll
  for (int ii=0; ii<2; ii++){
    int c = tid + ii*256;
    float hn = (out[ii]-mean)*r*sb_ng[c] + sb_nb[c];
    float e1 = eo[b*1024 + c], e2 = eo[b*1024 + 512 + c];
    float hm = hn*(1.f + e1) + e2;
    sbuf[(size_t)blk*512 + c] = siluf(hm);
  }
}

// ---------------- out = x + sbuf @ W + b (MFMA, 32-row tiles, in-place d_out) ----------------
__global__ __launch_bounds__(256) void k_out(const u16* __restrict__ wpk,
                      const float* __restrict__ bias, const float* __restrict__ x,
                      float* __restrict__ out){
  int r0 = blockIdx.x*32, tid = threadIdx.x;
  __shared__ u16 xs[32*520];
  { int row = tid >> 3, c0 = (tid & 7)*64;
    const f32x4* sp = (const f32x4*)(out + (size_t)(r0+row)*512 + c0);
#pragma unroll
    for (int j=0;j<8;j++){
      f32x4 va = sp[2*j], vb = sp[2*j+1];
      short8 o;
      o[0]=(short)f2bu(va[0]); o[1]=(short)f2bu(va[1]); o[2]=(short)f2bu(va[2]); o[3]=(short)f2bu(va[3]);
      o[4]=(short)f2bu(vb[0]); o[5]=(short)f2bu(vb[1]); o[6]=(short)f2bu(vb[2]); o[7]=(short)f2bu(vb[3]);
      *(short8*)&xs[row*520 + c0 + 8*j] = o;
    } }
  __syncthreads();
  int lane = tid & 63, w = tid >> 6;
  int n = lane & 15, q = lane >> 4;
  int mt = w & 1;
  short8 a_[16];
#pragma unroll
  for (int kc=0;kc<16;kc++) a_[kc] = *(const short8*)&xs[(mt*16 + n)*520 + kc*32 + q*8];
  const short8* bp = (const short8*)wpk;
#pragma unroll 1
  for (int i=0;i<16;i++){
    int nt = (w>>1)*16 + i;
    f32x4 acc = {0.f,0.f,0.f,0.f};
#pragma unroll
    for (int kc=0;kc<16;kc++) acc = MFMA16(a_[kc], bp[(nt*16+kc)*64 + lane], acc);
    int col = nt*16 + n;
    float bv = bias[col];
#pragma unroll
    for (int r=0;r<4;r++){
      size_t rowg = (size_t)(r0 + mt*16 + q*4 + r);
      out[rowg*512 + col] = acc[r] + bv + x[rowg*512 + col];
    }
  }
}

extern "C" void kernel_launch(void* const* d_in, const int* in_sizes, int n_in,
                              void* d_out, int out_size, void* d_ws, size_t ws_size,
                              hipStream_t stream) {
  (void)in_sizes; (void)n_in; (void)out_size; (void)ws_size;
  const float* x        = (const float*)d_in[0];
  const float* xf       = (const float*)d_in[1];
  const float* emb      = (const float*)d_in[2];
  const float* src_mask = (const float*)d_in[3];
  const float* norm_g   = (const float*)d_in[4];
  const float* norm_b   = (const float*)d_in[5];
  const float* tnorm_g  = (const float*)d_in[6];
  const float* tnorm_b  = (const float*)d_in[7];
  const float* m_pos    = (const float*)d_in[8];
  const float* m_gate   = (const float*)d_in[9];
  const float* m_fc1w   = (const float*)d_in[10];
  const float* m_fc1b   = (const float*)d_in[11];
  const float* m_fc2w   = (const float*)d_in[12];
  const float* m_fc2b   = (const float*)d_in[13];
  const float* m_projw  = (const float*)d_in[14];
  const float* m_projb  = (const float*)d_in[15];
  const float* t_pos    = (const float*)d_in[16];
  const float* t_gate   = (const float*)d_in[17];
  const float* t_fc1w   = (const float*)d_in[18];
  const float* t_fc1b   = (const float*)d_in[19];
  const float* t_fc2w   = (const float*)d_in[20];
  const float* t_fc2b   = (const float*)d_in[21];
  const float* t_projw  = (const float*)d_in[22];
  const float* t_projb  = (const float*)d_in[23];
  const float* body_w   = (const float*)d_in[24];
  const float* sb_embw  = (const float*)d_in[25];
  const float* sb_embb  = (const float*)d_in[26];
  const float* sb_ng    = (const float*)d_in[27];
  const float* sb_nb    = (const float*)d_in[28];
  const float* sb_outw  = (const float*)d_in[29];
  const float* sb_outb  = (const float*)d_in[30];
  const int*   cond     = (const int*)d_in[31];

  // ---- workspace (~133 MB), manual lifetime aliasing ----
  char* base = (char*)d_ws;
  size_t o = 0;
  auto alloc = [&](size_t bytes)->char*{ char* r = base + o; o += (bytes + 255) & ~(size_t)255; return r; };
  u16*  mf      = (u16*)alloc(67108864);    // motion_feat bf16, live to end
  char* R       = alloc(33554432);          // aliased region
  u16*  xtb     = (u16*)(R);                // [4928x256] bf16, dead after k_text_moe
  float* ycT    = (float*)(R + 4194304);    // [9856x256] f32, dead after k_text_combine
  u16*  ycM     = (u16*)(R);                // [262144x64] bf16, dead after k_mproj
  float* attnw  = (float*)(R);              // [512x4096] f32, written after ycM dead
  u16*  xmb     = (u16*)alloc(16777216);    // [131072x64] bf16
  u16*  t1pk    = (u16*)alloc(4194304);     // packed bf16 weights
  u16*  t2pk    = (u16*)alloc(4194304);
  u16*  m1pk    = (u16*)alloc(262144);
  u16*  m2pk    = (u16*)alloc(262144);
  u16*  mppk    = (u16*)alloc(32768);
  u16*  wopk    = (u16*)alloc(524288);
  int2* eidxT   = (int2*)alloc(39424);
  float2* ewT   = (float2*)alloc(39424);
  int2* eidxM   = (int2*)alloc(1048576);
  float2* ewM   = (float2*)alloc(1048576);
  int*  alistT  = (int*)alloc(39424);
  int*  alistM  = (int*)alloc(1048576);
  int*  cnts    = (int*)alloc(256);
  float* tfeat  = (float*)alloc(2523136);
  float* eo     = (float*)alloc(262144);
  float* bwv    = (float*)alloc(256);
  float* sbuf   = (float*)d_out;

  // setup
  k_zero<<<1, 64, 0, stream>>>(cnts);
  k_bw<<<1, 64, 0, stream>>>(body_w, bwv);
  k_repack<<<512, 256, 0, stream>>>(t_fc1w, t1pk, 8, 1024, 2097152);
  k_repack<<<512, 256, 0, stream>>>(t_fc2w, t2pk, 32, 256, 2097152);
  k_repack<<<64, 256, 0, stream>>>(m_fc1w, m1pk, 2, 256, 131072);
  k_repack<<<64, 256, 0, stream>>>(m_fc2w, m2pk, 8, 64, 131072);
  k_repack<<<8, 256, 0, stream>>>(m_projw, mppk, 2, 256, 16384);
  k_repack<<<128, 256, 0, stream>>>(sb_outw, wopk, 16, 512, 262144);
  k_eo<<<256, 256, 0, stream>>>(emb, sb_embw, sb_embb, eo);

  // pre + routing
  k_text_pre<<<4928, 256, 0, stream>>>(xf, tnorm_g, tnorm_b, t_pos, t_gate, xtb, eidxT, ewT);
  k_motion_pre<<<32768, 256, 0, stream>>>(x, norm_g, norm_b, m_pos, m_gate, xmb, eidxM, ewM);
  k_count<<<32, 256, 0, stream>>>(eidxT, 4928, cnts);
  k_count<<<256, 256, 0, stream>>>(eidxM, 131072, cnts + 8);
  k_scan<<<1, 64, 0, stream>>>(cnts);
  k_fill<<<32, 256, 0, stream>>>(eidxT, 4928, cnts + 32, alistT);
  k_fill<<<256, 256, 0, stream>>>(eidxM, 131072, cnts + 40, alistM);

  // text MoE (MFMA) then combine
  k_text_moe<<<dim3(308, 8), 256, 0, stream>>>(xtb, alistT, cnts, t1pk, t_fc1b, t2pk, t_fc2b, ycT);
  k_text_combine<<<4928, 128, 0, stream>>>(ycT, ewT, t_projw, t_projb, tfeat);

  // motion MoE (MFMA) then combine+proj (MFMA)
  k_motion_moe<<<dim3(4096, 8), 256, 0, stream>>>(xmb, alistM, cnts, m1pk, m_fc1b, m2pk, m_fc2b, ycM);
  k_mproj<<<4096, 256, 0, stream>>>(ycM, ewM, mppk, m_projb, mf);

  // attention + epilogue
  k_attn<<<512, 256, 0, stream>>>(tfeat, (const bf16*)mf, src_mask, cond, attnw);
  k_j1<<<16384, 256, 0, stream>>>((const bf16*)mf, attnw, bwv, eo, sb_ng, sb_nb, sbuf);
  k_out<<<512, 256, 0, stream>>>(wopk, sb_outb, x, (float*)d_out);
}

// Round 6
// 677.095 us; speedup vs baseline: 5.2081x; 1.1064x over previous
//
#include <hip/hip_runtime.h>
#include <hip/hip_bf16.h>

// STMA block, MI355X. Round 6: LDS-resident single-pass attention writing
// B-fragment-ready attnT (bf16), and k_j1 split into k_qs + MFMA k_yt + k_j2.
// MoE/proj/out MFMA pipeline unchanged from round 5.

typedef __hip_bfloat16 bf16;
typedef unsigned short u16;
typedef unsigned int   u32;
typedef __attribute__((ext_vector_type(8))) short short8;   // 8 bf16 = 4 VGPR
typedef __attribute__((ext_vector_type(4))) float f32x4;    // MFMA C/D

#define MFMA16(a,b,c) __builtin_amdgcn_mfma_f32_16x16x32_bf16(a,b,c,0,0,0)

__device__ __forceinline__ float b2f(bf16 v){ return __bfloat162float(v); }
__device__ __forceinline__ u16 f2bu(float f){
  union { __hip_bfloat16 hh; u16 us; } cv; cv.hh = __float2bfloat16(f); return cv.us;
}
__device__ __forceinline__ float bu2f(u16 v){ return __uint_as_float(((u32)v)<<16); }
__device__ __forceinline__ float geluf(float x){ return 0.5f*x*(1.0f+erff(x*0.7071067811865475f)); }
__device__ __forceinline__ float siluf(float x){ return x/(1.0f+expf(-x)); }

__device__ __forceinline__ float wsum(float v){
#pragma unroll
  for (int o=32;o>0;o>>=1) v += __shfl_xor(v,o,64);
  return v;
}
__device__ __forceinline__ float wmax(float v){
#pragma unroll
  for (int o=32;o>0;o>>=1) v = fmaxf(v, __shfl_xor(v,o,64));
  return v;
}
__device__ __forceinline__ void top2(const float* lg, int& i1, int& i2, float& wA){
  i1 = 0; float v1 = lg[0];
#pragma unroll
  for (int e=1;e<8;e++) if (lg[e] > v1){ v1 = lg[e]; i1 = e; }
  i2 = 0; float v2 = -1e30f;
#pragma unroll
  for (int e=0;e<8;e++) if (e != i1 && lg[e] > v2){ v2 = lg[e]; i2 = e; }
  wA = 1.f/(1.f + expf(v2 - v1));
}

// ---------------- utility kernels ----------------
__global__ __launch_bounds__(64) void k_zero(int* cnts){ cnts[threadIdx.x] = 0; }

__global__ __launch_bounds__(64) void k_bw(const float* __restrict__ body_w, float* __restrict__ bwv){
  int t = threadIdx.x;
  if (t < 8){
    float v[8]; float mx = -1e30f;
#pragma unroll
    for (int j=0;j<8;j++){ v[j] = body_w[t*8+j]; mx = fmaxf(mx, v[j]); }
    float s = 0.f;
#pragma unroll
    for (int j=0;j<8;j++){ v[j] = expf(v[j]-mx); s += v[j]; }
#pragma unroll
    for (int j=0;j<8;j++) bwv[t*8+j] = v[j]/s;
  }
}

// repack K x N weight (k-major, E experts) into B-fragment order, bf16.
__global__ __launch_bounds__(256) void k_repack(const float* __restrict__ s, u16* __restrict__ d,
                                                int KC, int N, int total){
  int NT = N >> 4;
  for (int t = blockIdx.x*256 + threadIdx.x; t < total; t += gridDim.x*256){
    int j = t & 7, n = (t>>3) & 15, q = (t>>7) & 3;
    int r2 = t >> 9;
    int kc = r2 % KC; int r3 = r2 / KC;
    int nt = r3 % NT; int e = r3 / NT;
    int k = kc*32 + q*8 + j;
    d[t] = f2bu(s[((size_t)(e*(KC*32) + k))*N + nt*16 + n]);
  }
}

__global__ __launch_bounds__(256) void k_count(const int2* __restrict__ eidx, int n, int* __restrict__ cnt){
  __shared__ int h[8];
  int tid = threadIdx.x;
  if (tid < 8) h[tid] = 0;
  __syncthreads();
  for (int i = blockIdx.x*256 + tid; i < n; i += gridDim.x*256){
    int2 e = eidx[i];
    atomicAdd(&h[e.x], 1); atomicAdd(&h[e.y], 1);
  }
  __syncthreads();
  if (tid < 8) atomicAdd(&cnt[tid], h[tid]);
}

// cnts: [0..7]=cntT [8..15]=cntM [16..23]=offT [24..31]=offM [32..39]=offT2 [40..47]=offM2
__global__ __launch_bounds__(64) void k_scan(int* cnts){
  if (threadIdx.x == 0){
    int s = 0;
    for (int e=0;e<8;e++){ cnts[16+e] = s; cnts[32+e] = s; s += cnts[e]; }
    s = 0;
    for (int e=0;e<8;e++){ cnts[24+e] = s; cnts[40+e] = s; s += cnts[8+e]; }
  }
}

__global__ __launch_bounds__(256) void k_fill(const int2* __restrict__ eidx, int n,
                                              int* __restrict__ off2, int* __restrict__ alist){
  __shared__ int lc[8], gb[8], lc2[8];
  int tid = threadIdx.x;
  if (tid < 8){ lc[tid] = 0; lc2[tid] = 0; }
  __syncthreads();
  for (int i = blockIdx.x*256 + tid; i < n; i += gridDim.x*256){
    int2 e = eidx[i];
    atomicAdd(&lc[e.x], 1); atomicAdd(&lc[e.y], 1);
  }
  __syncthreads();
  if (tid < 8) gb[tid] = atomicAdd(&off2[tid], lc[tid]);
  __syncthreads();
  for (int i = blockIdx.x*256 + tid; i < n; i += gridDim.x*256){
    int2 e = eidx[i];
    int s0 = atomicAdd(&lc2[e.x], 1); alist[gb[e.x] + s0] = i*2;
    int s1 = atomicAdd(&lc2[e.y], 1); alist[gb[e.y] + s1] = i*2 + 1;
  }
}

// ---------------- pre: LN + pos + gate ----------------
__global__ __launch_bounds__(256) void k_text_pre(
    const float* __restrict__ xf, const float* __restrict__ tg, const float* __restrict__ tb,
    const float* __restrict__ tpos, const float* __restrict__ gw,
    u16* __restrict__ xtb, int2* __restrict__ eidxT, float2* __restrict__ ewT){
  int tok = blockIdx.x, tid = threadIdx.x;
  int n = tok % 77;
  __shared__ float redw[32], lgs[8];
  int w = tid >> 6, ln = tid & 63;
  float xv = xf[tok*256 + tid];
  float s1 = wsum(xv);
  if (ln == 0) redw[w] = s1;
  __syncthreads();
  float mean = (redw[0]+redw[1]+redw[2]+redw[3]) * (1.f/256.f);
  __syncthreads();
  float c = xv - mean;
  float s2 = wsum(c*c);
  if (ln == 0) redw[w] = s2;
  __syncthreads();
  float var = (redw[0]+redw[1]+redw[2]+redw[3]) * (1.f/256.f);
  float r = rsqrtf(var + 1e-5f);
  float xn = c*r*tg[tid] + tb[tid] + tpos[n*256 + tid];
  xtb[tok*256 + tid] = f2bu(xn);
  __syncthreads();
  float lp[8];
#pragma unroll
  for (int e=0;e<8;e++) lp[e] = wsum(xn * gw[tid*8 + e]);
  if (ln == 0){
#pragma unroll
    for (int e=0;e<8;e++) redw[w*8+e] = lp[e];
  }
  __syncthreads();
  if (tid < 8) lgs[tid] = redw[tid] + redw[8+tid] + redw[16+tid] + redw[24+tid];
  __syncthreads();
  if (tid == 0){
    int i1, i2; float wA; top2(lgs, i1, i2, wA);
    eidxT[tok] = make_int2(i1, i2);
    ewT[tok] = make_float2(wA, 1.f - wA);
  }
}

__global__ __launch_bounds__(256) void k_motion_pre(
    const float* __restrict__ x, const float* __restrict__ ng, const float* __restrict__ nb,
    const float* __restrict__ mpos, const float* __restrict__ gw,
    u16* __restrict__ xmb, int2* __restrict__ eidxM, float2* __restrict__ ewM){
  int tok = blockIdx.x*4 + (threadIdx.x >> 6);
  int d = threadIdx.x & 63;
  float xv = x[(size_t)tok*64 + d];
  float m = wsum(xv) * (1.f/64.f);
  float c = xv - m;
  float var = wsum(c*c) * (1.f/64.f);
  float r = rsqrtf(var + 1e-5f);
  int h = tok & 7; int t = (tok >> 3) & 255;
  float xn = c*r*ng[d] + nb[d] + mpos[(t*8+h)*64 + d];
  xmb[(size_t)tok*64 + d] = f2bu(xn);
  float lg[8];
#pragma unroll
  for (int e=0;e<8;e++) lg[e] = wsum(xn * gw[d*8 + e]);
  if (d == 0){
    int i1, i2; float wA; top2(lg, i1, i2, wA);
    eidxM[tok] = make_int2(i1, i2);
    ewM[tok] = make_float2(wA, 1.f - wA);
  }
}

// ---------------- motion MoE (MFMA): 32-token tiles ----------------
__global__ __launch_bounds__(256) void k_motion_moe(
    const u16* __restrict__ xmb, const int* __restrict__ alistM, const int* __restrict__ cnts,
    const u16* __restrict__ w1pk, const float* __restrict__ fc1b,
    const u16* __restrict__ w2pk, const float* __restrict__ fc2b,
    u16* __restrict__ ycM){
  int e = blockIdx.y, tile = blockIdx.x, tid = threadIdx.x;
  int cnt = cnts[8+e]; int base = tile*32;
  if (base >= cnt) return;
  int nn = min(32, cnt - base); int off = cnts[24+e];
  __shared__ int toks[32];
  __shared__ u16 xs[32*72];
  __shared__ u16 hT[32*264];
  if (tid < 32) toks[tid] = alistM[off + base + min(tid, nn-1)];
  __syncthreads();
  { int row = tid >> 3, c0 = (tid & 7)*8;
    short8 v = *(const short8*)(xmb + (size_t)(toks[row]>>1)*64 + c0);
    *(short8*)&xs[row*72 + c0] = v; }
  __syncthreads();
  int lane = tid & 63, w = tid >> 6;
  int n = lane & 15, q = lane >> 4;
  int mt = w & 1;
  short8 a0 = *(const short8*)&xs[(mt*16 + n)*72 + q*8];
  short8 a1 = *(const short8*)&xs[(mt*16 + n)*72 + 32 + q*8];
  const short8* b1 = (const short8*)(w1pk + (size_t)e*16384);
#pragma unroll
  for (int i=0;i<8;i++){
    int nt = (w>>1)*8 + i;
    f32x4 acc = {0.f,0.f,0.f,0.f};
    acc = MFMA16(a0, b1[(nt*2+0)*64 + lane], acc);
    acc = MFMA16(a1, b1[(nt*2+1)*64 + lane], acc);
    float bias = fc1b[e*256 + nt*16 + n];
#pragma unroll
    for (int r=0;r<4;r++)
      hT[(mt*16 + q*4 + r)*264 + nt*16 + n] = f2bu(geluf(acc[r] + bias));
  }
  __syncthreads();
  short8 a2[8];
#pragma unroll
  for (int kc=0;kc<8;kc++) a2[kc] = *(const short8*)&hT[(mt*16 + n)*264 + kc*32 + q*8];
  const short8* b2 = (const short8*)(w2pk + (size_t)e*16384);
#pragma unroll
  for (int i=0;i<2;i++){
    int nt = (w>>1)*2 + i;
    f32x4 acc = {0.f,0.f,0.f,0.f};
#pragma unroll
    for (int kc=0;kc<8;kc++) acc = MFMA16(a2[kc], b2[(nt*8+kc)*64 + lane], acc);
    float bias = fc2b[e*64 + nt*16 + n];
#pragma unroll
    for (int r=0;r<4;r++){
      int row = mt*16 + q*4 + r;
      if (row < nn) ycM[(size_t)toks[row]*64 + nt*16 + n] = f2bu(acc[r] + bias);
    }
  }
}

// ---------------- text MoE (MFMA): 16-token tiles ----------------
__global__ __launch_bounds__(256) void k_text_moe(
    const u16* __restrict__ xtb, const int* __restrict__ alistT, const int* __restrict__ cnts,
    const u16* __restrict__ w1pk, const float* __restrict__ fc1b,
    const u16* __restrict__ w2pk, const float* __restrict__ fc2b,
    float* __restrict__ ycT){
  int e = blockIdx.y, tile = blockIdx.x, tid = threadIdx.x;
  int cnt = cnts[e]; int base = tile*16;
  if (base >= cnt) return;
  int nn = min(16, cnt - base); int off = cnts[16+e];
  __shared__ int toks[16];
  __shared__ u16 xs[16*264];
  __shared__ u16 hT[16*1032];
  if (tid < 16) toks[tid] = alistT[off + base + min(tid, nn-1)];
  __syncthreads();
  { int row = tid >> 4, c0 = (tid & 15)*16;
    const short8* sp = (const short8*)(xtb + (size_t)(toks[row]>>1)*256 + c0);
    short8 v0 = sp[0], v1 = sp[1];
    *(short8*)&xs[row*264 + c0] = v0;
    *(short8*)&xs[row*264 + c0 + 8] = v1; }
  __syncthreads();
  int lane = tid & 63, w = tid >> 6;
  int n = lane & 15, q = lane >> 4;
  short8 a_[8];
#pragma unroll
  for (int kc=0;kc<8;kc++) a_[kc] = *(const short8*)&xs[n*264 + kc*32 + q*8];
  const short8* b1 = (const short8*)(w1pk + (size_t)e*262144);
#pragma unroll 1
  for (int i=0;i<16;i++){
    int nt = w*16 + i;
    f32x4 acc = {0.f,0.f,0.f,0.f};
#pragma unroll
    for (int kc=0;kc<8;kc++) acc = MFMA16(a_[kc], b1[(nt*8+kc)*64 + lane], acc);
    float bias = fc1b[e*1024 + nt*16 + n];
#pragma unroll
    for (int r=0;r<4;r++)
      hT[(q*4 + r)*1032 + nt*16 + n] = f2bu(geluf(acc[r] + bias));
  }
  __syncthreads();
  const short8* b2 = (const short8*)(w2pk + (size_t)e*262144);
  f32x4 acc[4];
#pragma unroll
  for (int i=0;i<4;i++) acc[i] = (f32x4){0.f,0.f,0.f,0.f};
#pragma unroll 1
  for (int kc=0;kc<32;kc++){
    short8 a = *(const short8*)&hT[n*1032 + kc*32 + q*8];
#pragma unroll
    for (int i=0;i<4;i++){
      int nt = w*4 + i;
      acc[i] = MFMA16(a, b2[(nt*32+kc)*64 + lane], acc[i]);
    }
  }
#pragma unroll
  for (int i=0;i<4;i++){
    int nt = w*4 + i;
    float bias = fc2b[e*256 + nt*16 + n];
#pragma unroll
    for (int r=0;r<4;r++){
      int row = q*4 + r;
      if (row < nn) ycT[(size_t)toks[row]*256 + nt*16 + n] = acc[i][r] + bias;
    }
  }
}

// combine 2 expert contributions (gate-weighted), gelu, proj 256->128 -> tfeat
__global__ __launch_bounds__(128) void k_text_combine(
    const float* __restrict__ ycT, const float2* __restrict__ ewT,
    const float* __restrict__ pw, const float* __restrict__ pb,
    float* __restrict__ tfeat){
  int t = blockIdx.x, tid = threadIdx.x;
  __shared__ float gy[256];
  float2 w = ewT[t];
  for (int c=tid; c<256; c+=128){
    float y = w.x*ycT[(size_t)(t*2)*256 + c] + w.y*ycT[(size_t)(t*2+1)*256 + c];
    gy[c] = geluf(y);
  }
  __syncthreads();
  float a = pb[tid];
  for (int k=0;k<256;k++) a += gy[k] * pw[k*128 + tid];
  tfeat[(size_t)t*128 + tid] = a;
}

// motion combine + gelu + proj 64->256 (MFMA) -> mf bf16
__global__ __launch_bounds__(256) void k_mproj(
    const u16* __restrict__ ycM, const float2* __restrict__ ewM,
    const u16* __restrict__ wpk, const float* __restrict__ pb,
    u16* __restrict__ mf){
  int t0 = blockIdx.x*32, tid = threadIdx.x;
  __shared__ u16 xs[32*72];
  { int row = tid >> 3, c0 = (tid & 7)*8;
    int tok = t0 + row;
    float2 wgt = ewM[tok];
    short8 v0 = *(const short8*)(ycM + (size_t)(tok*2)*64 + c0);
    short8 v1 = *(const short8*)(ycM + (size_t)(tok*2+1)*64 + c0);
    short8 o;
#pragma unroll
    for (int j=0;j<8;j++)
      o[j] = (short)f2bu(geluf(wgt.x*bu2f((u16)v0[j]) + wgt.y*bu2f((u16)v1[j])));
    *(short8*)&xs[row*72 + c0] = o; }
  __syncthreads();
  int lane = tid & 63, w = tid >> 6;
  int n = lane & 15, q = lane >> 4;
  int mt = w & 1;
  short8 a0 = *(const short8*)&xs[(mt*16 + n)*72 + q*8];
  short8 a1 = *(const short8*)&xs[(mt*16 + n)*72 + 32 + q*8];
  const short8* bp = (const short8*)wpk;
#pragma unroll
  for (int i=0;i<8;i++){
    int nt = (w>>1)*8 + i;
    f32x4 acc = {0.f,0.f,0.f,0.f};
    acc = MFMA16(a0, bp[(nt*2+0)*64 + lane], acc);
    acc = MFMA16(a1, bp[(nt*2+1)*64 + lane], acc);
    float bias = pb[nt*16 + n];
#pragma unroll
    for (int r=0;r<4;r++){
      int tok = t0 + mt*16 + q*4 + r;
      mf[(size_t)tok*256 + nt*16 + n] = f2bu(acc[r] + bias);
    }
  }
}

// ---------------- eo = silu(emb) @ (2048x1024) + b ----------------
__global__ __launch_bounds__(256) void k_eo(const float* __restrict__ emb, const float* __restrict__ ew,
                     const float* __restrict__ ebias, float* __restrict__ eo){
  int b = blockIdx.x >> 2; int q = blockIdx.x & 3; int tid = threadIdx.x;
  __shared__ float se[2048];
#pragma unroll
  for (int i=0;i<8;i++){ int k = tid + 256*i; se[k] = siluf(emb[b*2048 + k]); }
  __syncthreads();
  int c = q*256 + tid;
  float a = ebias[c];
  for (int k=0;k<2048;k++) a += se[k] * ew[k*1024 + c];
  eo[b*1024 + c] = a;
}

// ---------------- attention: single-pass LDS-resident ----------------
// out: attnT bf16 [b,h][l][d]  (row l contiguous in d == B-fragment source layout)
__global__ __launch_bounds__(512) void k_attn(const float* __restrict__ tfeat, const u16* __restrict__ mf,
                       const float* __restrict__ src_mask, const int* __restrict__ cond,
                       u16* __restrict__ attnT){
  int b = blockIdx.x >> 3; int h = blockIdx.x & 7;
  int tid = threadIdx.x; int c = tid & 63; int part = tid >> 6;   // 8 parts
  __shared__ u16  kb[333*64];    // 42.6 KB: kv logits, then exp(kv-cm) in place
  __shared__ float vb[333*64];   // 85.2 KB
  __shared__ float colmax[64], colsum[64], red[512];
  float tc = ((cond[b] % 10) > 0) ? 1.f : 0.f;
  float negt = (1.f - tc) * (-1e6f);

  // stage K (bf16) + V (f32) and fold column max (c is fixed per thread)
  float mx = -1e30f;
  for (int idx = tid; idx < 333*64; idx += 512){
    int n = idx >> 6;
    float kv, vv;
    if (n < 77){
      const float* trow = tfeat + (b*77+n)*128;
      kv = trow[c] + negt;
      vv = trow[64 + c] * tc;
    } else {
      int t = n - 77; float smv = src_mask[b*256 + t];
      const u16* mrow = mf + ((size_t)(b*256+t)*8+h)*256;
      kv = bu2f(mrow[64 + c]) + (1.f - smv)*(-1e6f);
      vv = bu2f(mrow[128 + c]) * smv;
    }
    kb[idx] = f2bu(kv);
    vb[idx] = vv;
    mx = fmaxf(mx, kv);
  }
  red[tid] = mx; __syncthreads();
  if (part == 0){
    float m = red[c];
#pragma unroll
    for (int p=1;p<8;p++) m = fmaxf(m, red[p*64 + c]);
    colmax[c] = m;
  }
  __syncthreads();
  float cm = colmax[c];
  // exp in place + column sum
  float s = 0.f;
  for (int idx = tid; idx < 333*64; idx += 512){
    float e = expf(bu2f(kb[idx]) - cm);
    kb[idx] = f2bu(e);
    s += e;
  }
  red[tid] = s; __syncthreads();
  if (part == 0){
    float t = red[c];
#pragma unroll
    for (int p=1;p<8;p++) t += red[p*64 + c];
    colsum[c] = t;
  }
  __syncthreads();
  // accumulate attn[d=c][l0..l0+7] from LDS
  float acc[8];
#pragma unroll
  for (int j=0;j<8;j++) acc[j] = 0.f;
  int l0 = part*8;
  for (int n = 0; n < 333; n++){
    float e = bu2f(kb[n*64 + c]);               // conflict-free (2B/lane)
    const float* vr = vb + n*64 + l0;           // broadcast within wave
#pragma unroll
    for (int j=0;j<8;j++) acc[j] += e * vr[j];
  }
  float inv = 1.f / colsum[c];
  u16* outp = attnT + (size_t)(b*8+h)*4096;
#pragma unroll
  for (int j=0;j<8;j++)
    outp[(l0+j)*64 + c] = f2bu(acc[j]*inv);     // coalesced over c
}

// ---------------- q-softmax: qs[tok][d] = softmax(mf[tok][192..255]) ----------------
__global__ __launch_bounds__(256) void k_qs(const u16* __restrict__ mf, u16* __restrict__ qs){
  int tok = blockIdx.x*4 + (threadIdx.x >> 6);
  int d = threadIdx.x & 63;
  float v = bu2f(mf[(size_t)tok*256 + 192 + d]);
  float mx = wmax(v);
  float e = expf(v - mx);
  float s = wsum(e);
  qs[(size_t)tok*64 + d] = f2bu(e/s);
}

// ---------------- y_t = qs @ attn per (b,h): M=256,K=64,N=64 MFMA ----------------
__global__ __launch_bounds__(256) void k_yt(const u16* __restrict__ qs, const u16* __restrict__ attnT,
                                            u16* __restrict__ yt){
  int b = blockIdx.x >> 3; int h = blockIdx.x & 7;
  int tid = threadIdx.x;
  int lane = tid & 63, w = tid >> 6;
  int n = lane & 15, q = lane >> 4;
  const u16* qsb = qs + ((size_t)(b*256)*8 + h)*64;          // row stride 512 u16
  const u16* ab  = attnT + (size_t)(b*8+h)*4096;
  f32x4 acc[4][4];
#pragma unroll
  for (int mt=0;mt<4;mt++)
#pragma unroll
    for (int nt=0;nt<4;nt++) acc[mt][nt] = (f32x4){0.f,0.f,0.f,0.f};
#pragma unroll
  for (int kc=0;kc<2;kc++){
    short8 a_[4], b_[4];
#pragma unroll
    for (int mt=0;mt<4;mt++){
      int t = w*64 + mt*16 + n;
      a_[mt] = *(const short8*)(qsb + (size_t)t*512 + kc*32 + q*8);
    }
#pragma unroll
    for (int nt=0;nt<4;nt++){
      int l = nt*16 + n;
      b_[nt] = *(const short8*)(ab + l*64 + kc*32 + q*8);
    }
#pragma unroll
    for (int mt=0;mt<4;mt++)
#pragma unroll
      for (int nt=0;nt<4;nt++)
        acc[mt][nt] = MFMA16(a_[mt], b_[nt], acc[mt][nt]);
  }
#pragma unroll
  for (int mt=0;mt<4;mt++)
#pragma unroll
    for (int nt=0;nt<4;nt++){
      int l = nt*16 + n;
#pragma unroll
      for (int r=0;r<4;r++){
        int t = w*64 + mt*16 + q*4 + r;
        yt[((size_t)(b*256+t)*8 + h)*64 + l] = f2bu(acc[mt][nt][r]);
      }
    }
}

// ---------------- j2: body mix + y_t, LN(512), modulate, silu -> sbuf ----------------
__global__ __launch_bounds__(256) void k_j2(const u16* __restrict__ mf, const u16* __restrict__ yt,
                     const float* __restrict__ bwv, const float* __restrict__ eo,
                     const float* __restrict__ sb_ng, const float* __restrict__ sb_nb,
                     float* __restrict__ sbuf){
  int blk = blockIdx.x; int b = blk >> 8; int t = blk & 255;
  int tid = threadIdx.x;
  __shared__ float mfl[512], red[4];
#pragma unroll
  for (int ii=0; ii<2; ii++){
    int idx = tid + ii*256; int h = idx >> 6; int dd = idx & 63;
    mfl[idx] = bu2f(mf[((size_t)(b*256+t)*8+h)*256 + dd]);
  }
  __syncthreads();
  int w = tid >> 6, ln = tid & 63;
  float out[2];
#pragma unroll
  for (int ii=0; ii<2; ii++){
    int idx = tid + ii*256; int h = idx >> 6; int l = idx & 63;
    float a = bu2f(yt[((size_t)(b*256+t)*8 + h)*64 + l]);
    float bs = 0.f;
#pragma unroll
    for (int lh=0; lh<8; lh++) bs += bwv[h*8 + lh] * mfl[lh*64 + l];
    out[ii] = a + bs;
  }
  float psum = wsum(out[0] + out[1]);
  if (ln == 0) red[w] = psum;
  __syncthreads();
  float mean = (red[0]+red[1]+red[2]+red[3]) * (1.f/512.f);
  __syncthreads();
  float c0 = out[0]-mean, c1 = out[1]-mean;
  float pv = wsum(c0*c0 + c1*c1);
  if (ln == 0) red[w] = pv;
  __syncthreads();
  float var = (red[0]+red[1]+red[2]+red[3]) * (1.f/512.f);
  float r = rsqrtf(var + 1e-5f);
#pragma unroll
  for (int ii=0; ii<2; ii++){
    int c = tid + ii*256;
    float hn = (out[ii]-mean)*r*sb_ng[c] + sb_nb[c];
    float e1 = eo[b*1024 + c], e2 = eo[b*1024 + 512 + c];
    float hm = hn*(1.f + e1) + e2;
    sbuf[(size_t)blk*512 + c] = siluf(hm);
  }
}

// ---------------- out = x + sbuf @ W + b (MFMA, 32-row tiles, in-place d_out) ----------------
__global__ __launch_bounds__(256) void k_out(const u16* __restrict__ wpk,
                      const float* __restrict__ bias, const float* __restrict__ x,
                      float* __restrict__ out){
  int r0 = blockIdx.x*32, tid = threadIdx.x;
  __shared__ u16 xs[32*520];
  { int row = tid >> 3, c0 = (tid & 7)*64;
    const f32x4* sp = (const f32x4*)(out + (size_t)(r0+row)*512 + c0);
#pragma unroll
    for (int j=0;j<8;j++){
      f32x4 va = sp[2*j], vb = sp[2*j+1];
      short8 o;
      o[0]=(short)f2bu(va[0]); o[1]=(short)f2bu(va[1]); o[2]=(short)f2bu(va[2]); o[3]=(short)f2bu(va[3]);
      o[4]=(short)f2bu(vb[0]); o[5]=(short)f2bu(vb[1]); o[6]=(short)f2bu(vb[2]); o[7]=(short)f2bu(vb[3]);
      *(short8*)&xs[row*520 + c0 + 8*j] = o;
    } }
  __syncthreads();
  int lane = tid & 63, w = tid >> 6;
  int n = lane & 15, q = lane >> 4;
  int mt = w & 1;
  short8 a_[16];
#pragma unroll
  for (int kc=0;kc<16;kc++) a_[kc] = *(const short8*)&xs[(mt*16 + n)*520 + kc*32 + q*8];
  const short8* bp = (const short8*)wpk;
#pragma unroll 1
  for (int i=0;i<16;i++){
    int nt = (w>>1)*16 + i;
    f32x4 acc = {0.f,0.f,0.f,0.f};
#pragma unroll
    for (int kc=0;kc<16;kc++) acc = MFMA16(a_[kc], bp[(nt*16+kc)*64 + lane], acc);
    int col = nt*16 + n;
    float bv = bias[col];
#pragma unroll
    for (int r=0;r<4;r++){
      size_t rowg = (size_t)(r0 + mt*16 + q*4 + r);
      out[rowg*512 + col] = acc[r] + bv + x[rowg*512 + col];
    }
  }
}

extern "C" void kernel_launch(void* const* d_in, const int* in_sizes, int n_in,
                              void* d_out, int out_size, void* d_ws, size_t ws_size,
                              hipStream_t stream) {
  (void)in_sizes; (void)n_in; (void)out_size; (void)ws_size;
  const float* x        = (const float*)d_in[0];
  const float* xf       = (const float*)d_in[1];
  const float* emb      = (const float*)d_in[2];
  const float* src_mask = (const float*)d_in[3];
  const float* norm_g   = (const float*)d_in[4];
  const float* norm_b   = (const float*)d_in[5];
  const float* tnorm_g  = (const float*)d_in[6];
  const float* tnorm_b  = (const float*)d_in[7];
  const float* m_pos    = (const float*)d_in[8];
  const float* m_gate   = (const float*)d_in[9];
  const float* m_fc1w   = (const float*)d_in[10];
  const float* m_fc1b   = (const float*)d_in[11];
  const float* m_fc2w   = (const float*)d_in[12];
  const float* m_fc2b   = (const float*)d_in[13];
  const float* m_projw  = (const float*)d_in[14];
  const float* m_projb  = (const float*)d_in[15];
  const float* t_pos    = (const float*)d_in[16];
  const float* t_gate   = (const float*)d_in[17];
  const float* t_fc1w   = (const float*)d_in[18];
  const float* t_fc1b   = (const float*)d_in[19];
  const float* t_fc2w   = (const float*)d_in[20];
  const float* t_fc2b   = (const float*)d_in[21];
  const float* t_projw  = (const float*)d_in[22];
  const float* t_projb  = (const float*)d_in[23];
  const float* body_w   = (const float*)d_in[24];
  const float* sb_embw  = (const float*)d_in[25];
  const float* sb_embb  = (const float*)d_in[26];
  const float* sb_ng    = (const float*)d_in[27];
  const float* sb_nb    = (const float*)d_in[28];
  const float* sb_outw  = (const float*)d_in[29];
  const float* sb_outb  = (const float*)d_in[30];
  const int*   cond     = (const int*)d_in[31];

  // ---- workspace (~133 MB), manual lifetime aliasing ----
  char* base = (char*)d_ws;
  size_t o = 0;
  auto alloc = [&](size_t bytes)->char*{ char* r = base + o; o += (bytes + 255) & ~(size_t)255; return r; };
  u16*  mf      = (u16*)alloc(67108864);    // motion_feat bf16, live to end
  char* R       = alloc(33554432);          // aliased region
  u16*  xtb     = (u16*)(R);                // [4928x256] bf16, dead after k_text_moe
  float* ycT    = (float*)(R + 4194304);    // [9856x256] f32, dead after k_text_combine
  u16*  ycM     = (u16*)(R);                // [262144x64] bf16, dead after k_mproj
  u16*  attnT   = (u16*)(R);                // [512][64l][64d] bf16 (4 MB), written after ycM dead
  u16*  yt      = (u16*)(R + 8388608);      // [131072x8... [b,t,h,l] bf16 (16.8 MB)
  u16*  xmb     = (u16*)alloc(16777216);    // [131072x64] bf16, dead after k_motion_moe
  u16*  qs      = xmb;                      // q-softmax bf16, reuses xmb space
  u16*  t1pk    = (u16*)alloc(4194304);
  u16*  t2pk    = (u16*)alloc(4194304);
  u16*  m1pk    = (u16*)alloc(262144);
  u16*  m2pk    = (u16*)alloc(262144);
  u16*  mppk    = (u16*)alloc(32768);
  u16*  wopk    = (u16*)alloc(524288);
  int2* eidxT   = (int2*)alloc(39424);
  float2* ewT   = (float2*)alloc(39424);
  int2* eidxM   = (int2*)alloc(1048576);
  float2* ewM   = (float2*)alloc(1048576);
  int*  alistT  = (int*)alloc(39424);
  int*  alistM  = (int*)alloc(1048576);
  int*  cnts    = (int*)alloc(256);
  float* tfeat  = (float*)alloc(2523136);
  float* eo     = (float*)alloc(262144);
  float* bwv    = (float*)alloc(256);
  float* sbuf   = (float*)d_out;

  // setup
  k_zero<<<1, 64, 0, stream>>>(cnts);
  k_bw<<<1, 64, 0, stream>>>(body_w, bwv);
  k_repack<<<512, 256, 0, stream>>>(t_fc1w, t1pk, 8, 1024, 2097152);
  k_repack<<<512, 256, 0, stream>>>(t_fc2w, t2pk, 32, 256, 2097152);
  k_repack<<<64, 256, 0, stream>>>(m_fc1w, m1pk, 2, 256, 131072);
  k_repack<<<64, 256, 0, stream>>>(m_fc2w, m2pk, 8, 64, 131072);
  k_repack<<<8, 256, 0, stream>>>(m_projw, mppk, 2, 256, 16384);
  k_repack<<<128, 256, 0, stream>>>(sb_outw, wopk, 16, 512, 262144);
  k_eo<<<256, 256, 0, stream>>>(emb, sb_embw, sb_embb, eo);

  // pre + routing
  k_text_pre<<<4928, 256, 0, stream>>>(xf, tnorm_g, tnorm_b, t_pos, t_gate, xtb, eidxT, ewT);
  k_motion_pre<<<32768, 256, 0, stream>>>(x, norm_g, norm_b, m_pos, m_gate, xmb, eidxM, ewM);
  k_count<<<32, 256, 0, stream>>>(eidxT, 4928, cnts);
  k_count<<<256, 256, 0, stream>>>(eidxM, 131072, cnts + 8);
  k_scan<<<1, 64, 0, stream>>>(cnts);
  k_fill<<<32, 256, 0, stream>>>(eidxT, 4928, cnts + 32, alistT);
  k_fill<<<256, 256, 0, stream>>>(eidxM, 131072, cnts + 40, alistM);

  // text MoE (MFMA) then combine
  k_text_moe<<<dim3(308, 8), 256, 0, stream>>>(xtb, alistT, cnts, t1pk, t_fc1b, t2pk, t_fc2b, ycT);
  k_text_combine<<<4928, 128, 0, stream>>>(ycT, ewT, t_projw, t_projb, tfeat);

  // motion MoE (MFMA) then combine+proj (MFMA)
  k_motion_moe<<<dim3(4096, 8), 256, 0, stream>>>(xmb, alistM, cnts, m1pk, m_fc1b, m2pk, m_fc2b, ycM);
  k_mproj<<<4096, 256, 0, stream>>>(ycM, ewM, mppk, m_projb, mf);

  // attention + epilogue
  k_qs<<<32768, 256, 0, stream>>>(mf, qs);                   // overwrites xmb (dead)
  k_attn<<<512, 512, 0, stream>>>(tfeat, mf, src_mask, cond, attnT);
  k_yt<<<512, 256, 0, stream>>>(qs, attnT, yt);
  k_j2<<<16384, 256, 0, stream>>>(mf, yt, bwv, eo, sb_ng, sb_nb, sbuf);
  k_out<<<512, 256, 0, stream>>>(wopk, sb_outb, x, (float*)d_out);
}